// Round 10
// baseline (344.224 us; speedup 1.0000x reference)
//
#include <hip/hip_runtime.h>

// Problem constants (fixed by the reference): B=4, S=2048, D=DK=1024.
constexpr int Bc  = 4;
constexpr int Sc  = 2048;
constexpr int Dc  = 1024;
constexpr int DKc = 1024;
constexpr long BSc = (long)Bc * Sc;      // 8192 flattened rows of x

typedef __attribute__((ext_vector_type(8))) __bf16 bf16x8;
typedef __attribute__((ext_vector_type(4))) __bf16 bf16x4;
typedef __attribute__((ext_vector_type(4))) float  floatx4;

__device__ inline __bf16 f2bf(float f) {
  unsigned u = __builtin_bit_cast(unsigned, f);
  u = (u + 0x7FFFu + ((u >> 16) & 1u)) >> 16;      // RNE
  unsigned short s = (unsigned short)u;
  return __builtin_bit_cast(__bf16, s);
}
__device__ inline float bf2f(__bf16 h) {
  unsigned u = ((unsigned)__builtin_bit_cast(unsigned short, h)) << 16;
  return __builtin_bit_cast(float, u);
}

// async global->LDS, 16B per lane. lds base must be wave-uniform; HW scatters
// lane i's 16B to ldsbase + i*16.
__device__ inline void stage16(const __bf16* g, __bf16* l) {
  __builtin_amdgcn_global_load_lds(
      (const __attribute__((address_space(1))) unsigned int*)g,
      (__attribute__((address_space(3))) unsigned int*)l, 16, 0, 0);
}

__device__ __forceinline__ void bar_raw() {
  asm volatile("" ::: "memory");
  __builtin_amdgcn_s_barrier();
  asm volatile("" ::: "memory");
}
template <int N>
__device__ __forceinline__ void vmwait() {
  asm volatile("s_waitcnt vmcnt(%0)" :: "n"(N));
  __builtin_amdgcn_sched_barrier(0);
}

// ---------------------------------------------------------------------------
// prep: fp32->bf16 hi/lo splits, float4-vectorized (16B/lane, G13):
// x (8192 blks), WQ (1024), WK (1024); plus WV transpose (1024 blks).
// ---------------------------------------------------------------------------
__global__ __launch_bounds__(256) void prep(
    const float* __restrict__ x,  __bf16* __restrict__ xhi, __bf16* __restrict__ xlo,
    const float* __restrict__ wq, __bf16* __restrict__ qhi, __bf16* __restrict__ qlo,
    const float* __restrict__ wk, __bf16* __restrict__ khi, __bf16* __restrict__ klo,
    const float* __restrict__ wv, __bf16* __restrict__ vthi) {
  __shared__ float tile[32][33];
  long blk = blockIdx.x;
  if (blk >= 10240) {                 // WV transpose: Wt[dk][d] = W[d][dk]
    int t   = (int)(blk - 10240);
    int bx  = t & 31, by = t >> 5;
    int thx = threadIdx.x & 31, thy = threadIdx.x >> 5;   // 32 x 8
    int xI  = bx * 32 + thx, yI = by * 32 + thy;
#pragma unroll
    for (int j = 0; j < 32; j += 8)
      tile[thy + j][thx] = wv[(long)(yI + j) * DKc + xI];
    __syncthreads();
    int xO = by * 32 + thx, yO = bx * 32 + thy;
#pragma unroll
    for (int j = 0; j < 32; j += 8)
      vthi[(long)(yO + j) * Dc + xO] = f2bf(tile[thx][thy + j]);
    return;
  }
  const float* in; __bf16 *hi, *lo; long base;
  if (blk < 8192)      { in = x;  hi = xhi; lo = xlo; base = blk * 1024; }
  else if (blk < 9216) { in = wq; hi = qhi; lo = qlo; base = (blk - 8192) * 1024; }
  else                 { in = wk; hi = khi; lo = klo; base = (blk - 9216) * 1024; }
  long i = base + (long)threadIdx.x * 4;
  float4 f = *(const float4*)(in + i);
  __bf16 h0 = f2bf(f.x), h1 = f2bf(f.y), h2 = f2bf(f.z), h3 = f2bf(f.w);
  bf16x4 hv = {h0, h1, h2, h3};
  bf16x4 lv = {f2bf(f.x - bf2f(h0)), f2bf(f.y - bf2f(h1)),
               f2bf(f.z - bf2f(h2)), f2bf(f.w - bf2f(h3))};
  *(bf16x4*)(hi + i) = hv;
  *(bf16x4*)(lo + i) = lv;
}

// ---------------------------------------------------------------------------
// gemm_s7: S = T x^T (split, 3-MFMA) at 128x128/BK=32, 256 threads, 4 waves
// 2x2 (wave tile 64x64). R10: same THRICE-VERIFIED s5 schedule (counted
// vmcnt W=6, double-buffered, SAL/S2A/S2B order, 2 barriers/tile) at HALF
// the tile so LDS = 2 x 32 KB = 64 KB -> TWO co-resident blocks/CU whose
// independent barriers overlap one block's MFMA burst with the other's LDS
// burst (m114). R8's failure was the vmwait<0> drain, not the tile size.
// Ledger identical to s5: 8 loads/tile (SAL 2, S2A 3, S2B 3); prologue 14;
// steady W=6; tails <6,SAL> then <0>.
// Regions (elems): AH=0, BH=4096, BL=8192, AL=12288; buffer = 16384 (32 KB).
// ---------------------------------------------------------------------------
struct SCtx {
  const __bf16 *pAh, *pAl, *pBh, *pBl;  // per-thread staging src (row+swz col)
  __bf16* lds;
  int stLds;                             // wave*1024 (32 rows x 32 elems)
  int aoff, boff;                        // frag base offsets (elements)
};

template <int W, bool SAL, bool S2A, bool S2B>
__device__ __forceinline__ void tile_step(const SCtx& c, int t,
                                          floatx4 (&acc)[4][4]) {
  constexpr int K = 1024;
  constexpr int BH = 4096, BL = 8192, AL = 12288;   // region elem offsets
  __bf16* cur = c.lds + (t & 1) * 16384;
  __bf16* oth = c.lds + ((t & 1) ^ 1) * 16384;
  bf16x8 af[4], bfr[4], bfl[4];

  vmwait<W>();
  bar_raw();
  if (SAL) {  // stage Al_{t+1} into other buffer (readers passed bar 1)
    const __bf16* s = c.pAl + (t + 1) * 32;
    stage16(s, oth + AL + c.stLds);
    stage16(s + 16 * K, oth + AL + c.stLds + 512);
  }
#pragma unroll
  for (int mt = 0; mt < 4; ++mt)
    af[mt] = *(const bf16x8*)(cur + c.aoff + mt * 512);
#pragma unroll
  for (int nt = 0; nt < 4; ++nt)
    bfr[nt] = *(const bf16x8*)(cur + BH + c.boff + nt * 512);
#pragma unroll
  for (int nt = 0; nt < 4; ++nt)
    bfl[nt] = *(const bf16x8*)(cur + BL + c.boff + nt * 512);

  // ---- phases A+B in the same region as the reads ----
  __builtin_amdgcn_s_setprio(1);
#pragma unroll
  for (int mt = 0; mt < 4; ++mt)
#pragma unroll
    for (int nt = 0; nt < 4; ++nt)
      acc[mt][nt] = __builtin_amdgcn_mfma_f32_16x16x32_bf16(af[mt], bfr[nt], acc[mt][nt], 0, 0, 0);
#pragma unroll
  for (int mt = 0; mt < 4; ++mt)
#pragma unroll
    for (int nt = 0; nt < 4; ++nt)
      acc[mt][nt] = __builtin_amdgcn_mfma_f32_16x16x32_bf16(af[mt], bfl[nt], acc[mt][nt], 0, 0, 0);
  __builtin_amdgcn_s_setprio(0);

  bar_raw();   // all waves consumed AH/BH/BL -> safe to overwrite
  if (S2A) {   // Ah_{t+2} x2 + Bh_{t+2} #1 into cur
    const __bf16* sa = c.pAh + (t + 2) * 32;
    stage16(sa, cur + c.stLds);
    stage16(sa + 16 * K, cur + c.stLds + 512);
    stage16(c.pBh + (t + 2) * 32, cur + BH + c.stLds);
  }
  if (S2B) {   // Bh_{t+2} #2 + Bl_{t+2} x2
    stage16(c.pBh + (t + 2) * 32 + 16 * K, cur + BH + c.stLds + 512);
    const __bf16* sb = c.pBl + (t + 2) * 32;
    stage16(sb, cur + BL + c.stLds);
    stage16(sb + 16 * K, cur + BL + c.stLds + 512);
  }
  {
    // ---- phase C : acc += Al * Bh (afl reads overlap stage issue) ----
    bf16x8 afl[4];
#pragma unroll
    for (int mt = 0; mt < 4; ++mt)
      afl[mt] = *(const bf16x8*)(cur + AL + c.aoff + mt * 512);
    __builtin_amdgcn_s_setprio(1);
#pragma unroll
    for (int mt = 0; mt < 4; ++mt)
#pragma unroll
      for (int nt = 0; nt < 4; ++nt)
        acc[mt][nt] = __builtin_amdgcn_mfma_f32_16x16x32_bf16(afl[mt], bfr[nt], acc[mt][nt], 0, 0, 0);
    __builtin_amdgcn_s_setprio(0);
  }
}

__global__ __launch_bounds__(256, 2) void gemm_s7(
    const __bf16* __restrict__ thi, const __bf16* __restrict__ tlo,
    const __bf16* __restrict__ xhi, const __bf16* __restrict__ xlo,
    __bf16* __restrict__ P, float* __restrict__ Pmax, float* __restrict__ Psum) {
  __shared__ __align__(16) __bf16 smem[32768];   // 64 KB: 2 x {Ah,Bh,Bl,Al}
  constexpr int K = 1024;
  const int b    = blockIdx.z;
  const int m0   = blockIdx.y * 128;
  const int n0   = blockIdx.x * 128;
  const int wave = threadIdx.x >> 6;
  const int lane = threadIdx.x & 63;
  const int wm   = wave >> 1;            // 0..1
  const int wn   = wave & 1;             // 0..1
  const int sr   = lane >> 2;
  const int scol = ((lane & 3) ^ ((sr >> 1) & 3)) * 8;   // chunk-XOR swizzle
  const int frow = lane & 15;
  const int pko  = ((lane >> 4) ^ ((frow >> 1) & 3)) * 8;

  SCtx c;
  const long batch = (long)Sc * 1024;
  const long ar = (long)(m0 + wave * 32 + sr) * K + scol;
  const long br = (long)(n0 + wave * 32 + sr) * K + scol;
  c.pAh = thi + (long)b * batch + ar;
  c.pAl = tlo + (long)b * batch + ar;
  c.pBh = xhi + (long)b * batch + br;
  c.pBl = xlo + (long)b * batch + br;
  c.lds = smem;
  c.stLds = wave * 1024;
  c.aoff = (wm * 64 + frow) * 32 + pko;
  c.boff = (wn * 64 + frow) * 32 + pko;

  // Prologue: tile0 {Ah,Bh,Bl,Al} + tile1 {Ah,Bh,Bl} (FIFO-order-critical).
  {
    __bf16* b0 = smem;
    __bf16* b1 = smem + 16384;
    stage16(c.pAh, b0 + c.stLds);               stage16(c.pAh + 16 * K, b0 + c.stLds + 512);
    stage16(c.pBh, b0 + 4096 + c.stLds);        stage16(c.pBh + 16 * K, b0 + 4096 + c.stLds + 512);
    stage16(c.pBl, b0 + 8192 + c.stLds);        stage16(c.pBl + 16 * K, b0 + 8192 + c.stLds + 512);
    stage16(c.pAl, b0 + 12288 + c.stLds);       stage16(c.pAl + 16 * K, b0 + 12288 + c.stLds + 512);
    stage16(c.pAh + 32, b1 + c.stLds);          stage16(c.pAh + 32 + 16 * K, b1 + c.stLds + 512);
    stage16(c.pBh + 32, b1 + 4096 + c.stLds);   stage16(c.pBh + 32 + 16 * K, b1 + 4096 + c.stLds + 512);
    stage16(c.pBl + 32, b1 + 8192 + c.stLds);   stage16(c.pBl + 32 + 16 * K, b1 + 8192 + c.stLds + 512);
  }

  floatx4 acc[4][4];
  const floatx4 zero = {0.f, 0.f, 0.f, 0.f};
#pragma unroll
  for (int i = 0; i < 4; ++i)
#pragma unroll
    for (int j = 0; j < 4; ++j) acc[i][j] = zero;

#pragma unroll 1
  for (int t = 0; t < 30; ++t) tile_step<6, true, true, true>(c, t, acc);
  tile_step<6, true, false, false>(c, 30, acc);
  tile_step<0, false, false, false>(c, 31, acc);

  // ---- epilogue: softmax-over-q partials + p = exp(s - M_t) ----
  // (R8-verified 128^2 column-softmax + swizzled P store.)
  const int crow0 = (lane >> 4) * 4;
  const int ccol  = lane & 15;
  const int tid   = threadIdx.x;
  constexpr float scale = 0.03125f;
  float* smax = (float*)smem;            // [2][128]
  float* ssum = smax + 256;              // [2][128]

  float cm[4];
#pragma unroll
  for (int nt = 0; nt < 4; ++nt) {
    float mx = -3.0e38f;
#pragma unroll
    for (int mt = 0; mt < 4; ++mt)
#pragma unroll
      for (int r = 0; r < 4; ++r) mx = fmaxf(mx, acc[mt][nt][r] * scale);
    cm[nt] = mx;
  }
#pragma unroll
  for (int off = 16; off <= 32; off <<= 1)
#pragma unroll
    for (int nt = 0; nt < 4; ++nt)
      cm[nt] = fmaxf(cm[nt], __shfl_xor(cm[nt], off, 64));
  __syncthreads();
  if (lane < 16)
#pragma unroll
    for (int nt = 0; nt < 4; ++nt)
      smax[wm * 128 + wn * 64 + nt * 16 + lane] = cm[nt];
  __syncthreads();
  float mfin[4];
#pragma unroll
  for (int nt = 0; nt < 4; ++nt) {
    int cidx = wn * 64 + nt * 16 + ccol;
    mfin[nt] = fmaxf(smax[cidx], smax[128 + cidx]);
  }
  float ps[4];
#pragma unroll
  for (int nt = 0; nt < 4; ++nt) {
    float s = 0.f;
#pragma unroll
    for (int mt = 0; mt < 4; ++mt)
#pragma unroll
      for (int r = 0; r < 4; ++r)
        s += __expf(acc[mt][nt][r] * scale - mfin[nt]);
    ps[nt] = s;
  }
#pragma unroll
  for (int off = 16; off <= 32; off <<= 1)
#pragma unroll
    for (int nt = 0; nt < 4; ++nt) ps[nt] += __shfl_xor(ps[nt], off, 64);
  if (lane < 16)
#pragma unroll
    for (int nt = 0; nt < 4; ++nt)
      ssum[wm * 128 + wn * 64 + nt * 16 + lane] = ps[nt];
  __syncthreads();
  if (tid < 128) {
    long o = ((long)b * 16 + blockIdx.y) * Sc + n0 + tid;
    Pmax[o] = fmaxf(smax[tid], smax[128 + tid]);
    Psum[o] = ssum[tid] + ssum[128 + tid];
  }
  __syncthreads();
  // p -> bf16 via bit4-5 XOR-swizzled LDS round-trip, coalesced 16B stores.
  __bf16* sT = smem;                     // [128][128] = 32 KB
#pragma unroll
  for (int nt = 0; nt < 4; ++nt) {
    int col = wn * 64 + nt * 16 + ccol;
#pragma unroll
    for (int mt = 0; mt < 4; ++mt) {
      int rowb = wm * 64 + mt * 16 + crow0;
#pragma unroll
      for (int r = 0; r < 4; ++r) {
        int row = rowb + r;
        sT[row * 128 + (col ^ (((row >> 2) & 3) << 4))] =
            f2bf(__expf(acc[mt][nt][r] * scale - mfin[nt]));
      }
    }
  }
  __syncthreads();
  __bf16* Pb = P + (long)b * ((long)Sc * Sc);
#pragma unroll
  for (int cc = 0; cc < 8; ++cc) {
    int flat = cc * 2048 + tid * 8;
    int row = flat >> 7, col = flat & 127;
    *(bf16x8*)(Pb + (long)(m0 + row) * Sc + n0 + col) =
        *(const bf16x8*)(sT + row * 128 + (col ^ (((row >> 2) & 3) << 4)));
  }
}

// ---------------------------------------------------------------------------
// t5 body: T = x * G (split, 3-MFMA) at 256x128/BK=32, 512 threads, 8 waves
// as 4x2 (wave tile 64x64). 2 barriers/tile (R6, verified R7). Single vmwait
// W=4; tails <4,SAL> then <0>.
// ---------------------------------------------------------------------------
struct TCtx {
  const __bf16 *pAh, *pAl, *pBh, *pBl;
  __bf16* lds;
  int stA, stB;                          // wave*1024 (A), wave*512 (B)
  int aoff, boff;
};

template <int W, bool SAL, bool S2AB, bool S2B>
__device__ __forceinline__ void tile_step_t(const TCtx& c, int t,
                                            floatx4 (&acc)[4][4]) {
  constexpr int K = 1024;
  constexpr int BH = 8192, BL = 12288, AL = 16384, BUF = 24576;
  __bf16* cur = c.lds + (t & 1) * BUF;
  __bf16* oth = c.lds + ((t & 1) ^ 1) * BUF;
  bf16x8 af[4], bfr[4], bfl[4], afl[4];

  vmwait<W>();
  bar_raw();
  if (SAL) {
    const __bf16* s = c.pAl + (t + 1) * 32;
    stage16(s, oth + AL + c.stA);
    stage16(s + 16 * K, oth + AL + c.stA + 512);
  }
#pragma unroll
  for (int mt = 0; mt < 4; ++mt)
    af[mt] = *(const bf16x8*)(cur + c.aoff + mt * 512);
#pragma unroll
  for (int nt = 0; nt < 4; ++nt)
    bfr[nt] = *(const bf16x8*)(cur + BH + c.boff + nt * 512);
#pragma unroll
  for (int nt = 0; nt < 4; ++nt)
    bfl[nt] = *(const bf16x8*)(cur + BL + c.boff + nt * 512);
#pragma unroll
  for (int mt = 0; mt < 4; ++mt)
    afl[mt] = *(const bf16x8*)(cur + AL + c.aoff + mt * 512);

  __builtin_amdgcn_s_setprio(1);
#pragma unroll
  for (int mt = 0; mt < 4; ++mt)
#pragma unroll
    for (int nt = 0; nt < 4; ++nt)
      acc[mt][nt] = __builtin_amdgcn_mfma_f32_16x16x32_bf16(af[mt], bfr[nt], acc[mt][nt], 0, 0, 0);
#pragma unroll
  for (int mt = 0; mt < 4; ++mt)
#pragma unroll
    for (int nt = 0; nt < 4; ++nt)
      acc[mt][nt] = __builtin_amdgcn_mfma_f32_16x16x32_bf16(af[mt], bfl[nt], acc[mt][nt], 0, 0, 0);
#pragma unroll
  for (int mt = 0; mt < 4; ++mt)
#pragma unroll
    for (int nt = 0; nt < 4; ++nt)
      acc[mt][nt] = __builtin_amdgcn_mfma_f32_16x16x32_bf16(afl[mt], bfr[nt], acc[mt][nt], 0, 0, 0);
  __builtin_amdgcn_s_setprio(0);

  bar_raw();   // all reads consumed -> safe to overwrite cur
  if (S2AB) {
    const __bf16* sa = c.pAh + (t + 2) * 32;
    stage16(sa, cur + c.stA);
    stage16(sa + 16 * K, cur + c.stA + 512);
    stage16(c.pBh + (t + 2) * 32, cur + BH + c.stB);
  }
  if (S2B) stage16(c.pBl + (t + 2) * 32, cur + BL + c.stB);
}

__device__ void t5_body(__bf16* smem,
    const __bf16* __restrict__ xhi, const __bf16* __restrict__ xlo,
    const __bf16* __restrict__ gthi, const __bf16* __restrict__ gtlo,
    __bf16* __restrict__ thi, __bf16* __restrict__ tlo, int bx, int by) {
  constexpr int K = 1024;
  const int m0   = by * 256;
  const int n0   = bx * 128;
  const int wave = threadIdx.x >> 6;
  const int lane = threadIdx.x & 63;
  const int wm   = wave >> 1;            // 0..3
  const int wn   = wave & 1;             // 0..1
  const int sr   = lane >> 2;
  const int scol = ((lane & 3) ^ ((sr >> 1) & 3)) * 8;
  const int frow = lane & 15;
  const int pko  = ((lane >> 4) ^ ((frow >> 1) & 3)) * 8;

  TCtx c;
  const long ar = (long)(m0 + wave * 32 + sr) * K + scol;
  const long br = (long)(n0 + wave * 16 + sr) * K + scol;
  c.pAh = xhi + ar;
  c.pAl = xlo + ar;
  c.pBh = gthi + br;
  c.pBl = gtlo + br;
  c.lds = smem;
  c.stA = wave * 1024;
  c.stB = wave * 512;
  c.aoff = (wm * 64 + frow) * 32 + pko;
  c.boff = (wn * 64 + frow) * 32 + pko;

  // Prologue (FIFO-order-critical): Ah0 x2, Bh0, Bl0, Al0 x2, Ah1 x2, Bh1, Bl1.
  {
    __bf16* b0 = smem;
    __bf16* b1 = smem + 24576;
    stage16(c.pAh, b0 + c.stA);          stage16(c.pAh + 16 * K, b0 + c.stA + 512);
    stage16(c.pBh, b0 + 8192 + c.stB);
    stage16(c.pBl, b0 + 12288 + c.stB);
    stage16(c.pAl, b0 + 16384 + c.stA);  stage16(c.pAl + 16 * K, b0 + 16384 + c.stA + 512);
    stage16(c.pAh + 32, b1 + c.stA);     stage16(c.pAh + 32 + 16 * K, b1 + c.stA + 512);
    stage16(c.pBh + 32, b1 + 8192 + c.stB);
    stage16(c.pBl + 32, b1 + 12288 + c.stB);
  }

  floatx4 acc[4][4];
  const floatx4 zero = {0.f, 0.f, 0.f, 0.f};
#pragma unroll
  for (int i = 0; i < 4; ++i)
#pragma unroll
    for (int j = 0; j < 4; ++j) acc[i][j] = zero;

#pragma unroll 1
  for (int t = 0; t < 30; ++t) tile_step_t<4, true, true, true>(c, t, acc);
  tile_step_t<4, true, false, false>(c, 30, acc);
  tile_step_t<0, false, false, false>(c, 31, acc);

  // ---- epilogue: hi/lo split via XOR-swizzled [256][128] LDS round-trip ----
  const int crow0 = (lane >> 4) * 4;
  const int ccol  = lane & 15;
  const int tid   = threadIdx.x;
  __bf16* sT = smem;                     // 64 KB
#pragma unroll 1
  for (int pass = 0; pass < 2; ++pass) {
    __syncthreads();
#pragma unroll
    for (int nt = 0; nt < 4; ++nt) {
      int col = wn * 64 + nt * 16 + ccol;
#pragma unroll
      for (int mt = 0; mt < 4; ++mt) {
        int rowb = wm * 64 + mt * 16 + crow0;
#pragma unroll
        for (int r = 0; r < 4; ++r) {
          int row = rowb + r;
          float v = acc[mt][nt][r];
          __bf16 h = f2bf(v);
          sT[row * 128 + (col ^ (((row >> 2) & 3) << 4))] =
              pass ? f2bf(v - bf2f(h)) : h;
        }
      }
    }
    __syncthreads();
    __bf16* dst = pass ? tlo : thi;
#pragma unroll
    for (int cc = 0; cc < 8; ++cc) {
      int flat = cc * 4096 + tid * 8;
      int row = flat >> 7, col = flat & 127;
      *(bf16x8*)(dst + (long)(m0 + row) * DKc + n0 + col) =
          *(const bf16x8*)(sT + row * 128 + (col ^ (((row >> 2) & 3) << 4)));
    }
  }
}

// ---------------------------------------------------------------------------
// Shared 2-phase/3-buffer counted-vmcnt NT GEMM step (R6: ONE barrier/tile).
// {vmwait W, bar, 6 stages, 16 reads, 32 MFMA}. Steady W=6; tails
// <6,no-stg> then <0>. Verified R7.
// Buffer regions (elems): A0=0, A1=8192, B0=16384, B1=20480; buffer=24576.
// ---------------------------------------------------------------------------
struct PCtx {
  const __bf16 *pA, *pB;
  int stA, stB;                          // wave*1024 (A), wave*512 (B)
  int aoff, boff;
};

template <int KK, int W, bool STG>
__device__ __forceinline__ void tile_step_pv(const PCtx& c, int t,
                                             __bf16* cur, __bf16* dst,
                                             floatx4 (&acc)[4][4]) {
  vmwait<W>();
  bar_raw();
  if (STG) {
    const __bf16* a = c.pA + (t + 2) * 64;
    stage16(a, dst + c.stA);
    stage16(a + 16 * KK, dst + c.stA + 512);
    stage16(c.pB + (t + 2) * 64, dst + 16384 + c.stB);
    stage16(a + 32, dst + 8192 + c.stA);
    stage16(a + 32 + 16 * KK, dst + 8192 + c.stA + 512);
    stage16(c.pB + (t + 2) * 64 + 32, dst + 20480 + c.stB);
  }
  bf16x8 a0[4], b0[4], a1[4], b1[4];
#pragma unroll
  for (int mt = 0; mt < 4; ++mt)
    a0[mt] = *(const bf16x8*)(cur + c.aoff + mt * 512);
#pragma unroll
  for (int nt = 0; nt < 4; ++nt)
    b0[nt] = *(const bf16x8*)(cur + 16384 + c.boff + nt * 512);
#pragma unroll
  for (int mt = 0; mt < 4; ++mt)
    a1[mt] = *(const bf16x8*)(cur + 8192 + c.aoff + mt * 512);
#pragma unroll
  for (int nt = 0; nt < 4; ++nt)
    b1[nt] = *(const bf16x8*)(cur + 20480 + c.boff + nt * 512);
  __builtin_amdgcn_s_setprio(1);
#pragma unroll
  for (int mt = 0; mt < 4; ++mt)
#pragma unroll
    for (int nt = 0; nt < 4; ++nt)
      acc[mt][nt] = __builtin_amdgcn_mfma_f32_16x16x32_bf16(a0[mt], b0[nt], acc[mt][nt], 0, 0, 0);
#pragma unroll
  for (int mt = 0; mt < 4; ++mt)
#pragma unroll
    for (int nt = 0; nt < 4; ++nt)
      acc[mt][nt] = __builtin_amdgcn_mfma_f32_16x16x32_bf16(a1[mt], b1[nt], acc[mt][nt], 0, 0, 0);
  __builtin_amdgcn_s_setprio(0);
}

// ---------------------------------------------------------------------------
// v4 body: Vt = (x*WV)^T, 1-barrier pipeline (KK=1024, 16 K-tiles).
// Epilogue: transpose via padded LDS [128][VSTR2=264], 16B stores.
// ---------------------------------------------------------------------------
constexpr int VSTR2 = 264;

__device__ void v4_body(__bf16* smem,
    const __bf16* __restrict__ xhi, const __bf16* __restrict__ wvthi,
    __bf16* __restrict__ vt, int bx, int by) {
  constexpr int K = 1024;
  const int m0   = by * 256;             // seq (flattened b*S)
  const int n0   = bx * 128;             // dk
  const int wave = threadIdx.x >> 6;
  const int lane = threadIdx.x & 63;
  const int wm   = wave >> 1;            // 0..3
  const int wn   = wave & 1;             // 0..1
  const int sr   = lane >> 2;
  const int scol = ((lane & 3) ^ ((sr >> 1) & 3)) * 8;
  const int frow = lane & 15;
  const int pko  = ((lane >> 4) ^ ((frow >> 1) & 3)) * 8;

  PCtx c;
  c.pA = xhi + (long)(m0 + wave * 32 + sr) * K + scol;
  c.pB = wvthi + (long)(n0 + wave * 16 + sr) * K + scol;
  c.stA = wave * 1024;
  c.stB = wave * 512;
  c.aoff = (wm * 64 + frow) * 32 + pko;
  c.boff = (wn * 64 + frow) * 32 + pko;

  __bf16* B0 = smem;
  __bf16* B1 = smem + 24576;
  __bf16* B2 = smem + 49152;

  // Prologue (FIFO-order-critical): t0 {A0 x2, B0, A1 x2, B1}, t1 same.
  stage16(c.pA, B0 + c.stA);            stage16(c.pA + 16 * K, B0 + c.stA + 512);
  stage16(c.pB, B0 + 16384 + c.stB);
  stage16(c.pA + 32, B0 + 8192 + c.stA); stage16(c.pA + 32 + 16 * K, B0 + 8192 + c.stA + 512);
  stage16(c.pB + 32, B0 + 20480 + c.stB);
  stage16(c.pA + 64, B1 + c.stA);       stage16(c.pA + 64 + 16 * K, B1 + c.stA + 512);
  stage16(c.pB + 64, B1 + 16384 + c.stB);
  stage16(c.pA + 96, B1 + 8192 + c.stA); stage16(c.pA + 96 + 16 * K, B1 + 8192 + c.stA + 512);
  stage16(c.pB + 96, B1 + 20480 + c.stB);

  floatx4 acc[4][4];
  const floatx4 zero = {0.f, 0.f, 0.f, 0.f};
#pragma unroll
  for (int i = 0; i < 4; ++i)
#pragma unroll
    for (int j = 0; j < 4; ++j) acc[i][j] = zero;

#pragma unroll 1
  for (int t = 0; t < 12; t += 3) {
    tile_step_pv<1024, 6, true>(c, t,     B0, B2, acc);
    tile_step_pv<1024, 6, true>(c, t + 1, B1, B0, acc);
    tile_step_pv<1024, 6, true>(c, t + 2, B2, B1, acc);
  }
  tile_step_pv<1024, 6, true >(c, 12, B0, B2, acc);
  tile_step_pv<1024, 6, true >(c, 13, B1, B0, acc);
  tile_step_pv<1024, 6, false>(c, 14, B2, B2, acc);
  tile_step_pv<1024, 0, false>(c, 15, B0, B0, acc);

  // ---- epilogue: transpose via padded LDS, 16B stores to vt[b][dk][s] ----
  const int crow0 = (lane >> 4) * 4;
  const int ccol  = lane & 15;
  const int tid   = threadIdx.x;
  __syncthreads();
  __bf16* sT = smem;                     // [128][VSTR2]
#pragma unroll
  for (int nt = 0; nt < 4; ++nt) {
    int nl = wn * 64 + nt * 16 + ccol;   // dk-local 0..127
#pragma unroll
    for (int mt = 0; mt < 4; ++mt) {
      int ml = wm * 64 + mt * 16 + crow0;  // seq-local 0..255
#pragma unroll
      for (int r = 0; r < 4; ++r)
        sT[(long)nl * VSTR2 + ml + r] = f2bf(acc[mt][nt][r]);
    }
  }
  __syncthreads();
  const int bb   = m0 >> 11;            // tile fully within one batch
  const int seq0 = m0 & (Sc - 1);
  __bf16* dst = vt + (long)bb * DKc * Sc + seq0;
#pragma unroll
  for (int cc = 0; cc < 8; ++cc) {
    int flat = cc * 4096 + tid * 8;     // logical 128x256; 16B per thread
    int row = flat >> 8, col = flat & 255;
    *(bf16x8*)(dst + (long)(n0 + row) * Sc + col) =
        *(const bf16x8*)(sT + (long)row * VSTR2 + col);
  }
}

// ---------------------------------------------------------------------------
// gemm_tv: fused T-GEMM (blocks 0..255) + V-GEMM (blocks 256..511).
// Verified R9 (tail overlap win).
// ---------------------------------------------------------------------------
__global__ __launch_bounds__(512, 2) void gemm_tv(
    const __bf16* __restrict__ xhi, const __bf16* __restrict__ xlo,
    const __bf16* __restrict__ gthi, const __bf16* __restrict__ gtlo,
    __bf16* __restrict__ thi, __bf16* __restrict__ tlo,
    const __bf16* __restrict__ wvthi, __bf16* __restrict__ vt) {
  __shared__ __align__(16) __bf16 smem[73728];   // 144 KB (v-part max)
  int bid = blockIdx.x;
  if (bid < 256) {
    t5_body(smem, xhi, xlo, gthi, gtlo, thi, tlo, bid & 7, bid >> 3);
  } else {
    bid -= 256;
    v4_body(smem, xhi, wvthi, vt, bid & 7, bid >> 3);
  }
}

// ---------------------------------------------------------------------------
// scale_p: P <- P .* ffac[b][t(q)][k]  (elementwise, memory-bound).
// q-tiles are 128 rows (gemm_s7).
// ---------------------------------------------------------------------------
__global__ __launch_bounds__(256) void scale_p(__bf16* __restrict__ P,
                                               const float* __restrict__ ffac) {
  long i8 = (long)blockIdx.x * 256 + threadIdx.x;
  long base = i8 * 8;
  int k = (int)(base & (Sc - 1));
  int q = (int)((base >> 11) & (Sc - 1));
  int b = (int)(base >> 22);
  int t = q >> 7;                         // 128-row q-tiles
  const float* f = ffac + (((long)b * 16 + t) << 11) + k;
  float4 f0 = *(const float4*)f;
  float4 f1 = *(const float4*)(f + 4);
  bf16x8 p = *(const bf16x8*)(P + base);
  bf16x8 o;
  o[0] = f2bf(bf2f(p[0]) * f0.x);
  o[1] = f2bf(bf2f(p[1]) * f0.y);
  o[2] = f2bf(bf2f(p[2]) * f0.z);
  o[3] = f2bf(bf2f(p[3]) * f0.w);
  o[4] = f2bf(bf2f(p[4]) * f1.x);
  o[5] = f2bf(bf2f(p[5]) * f1.y);
  o[6] = f2bf(bf2f(p[6]) * f1.z);
  o[7] = f2bf(bf2f(p[7]) * f1.w);
  *(bf16x8*)(P + base) = o;
}

// ---------------------------------------------------------------------------
// gemm_pv4: out = attn @ Vt^T, plain NT GEMM (1-barrier pipeline). Verified R7.
// ---------------------------------------------------------------------------
__global__ __launch_bounds__(512, 2) void gemm_pv4(
    const __bf16* __restrict__ P, const __bf16* __restrict__ vt,
    float* __restrict__ out) {
  __shared__ __align__(16) __bf16 smem[73728];   // 144 KB = 3 x 48 KB buffers
  constexpr int K = 2048;
  const int b    = blockIdx.z;
  const int m0   = blockIdx.x * 256;     // q   (x=q: P-panel XCD locality)
  const int n0   = blockIdx.y * 128;     // dk
  const int wave = threadIdx.x >> 6;
  const int lane = threadIdx.x & 63;
  const int wm   = wave >> 1;            // 0..3
  const int wn   = wave & 1;             // 0..1
  const int sr   = lane >> 2;
  const int scol = ((lane & 3) ^ ((sr >> 1) & 3)) * 8;
  const int frow = lane & 15;
  const int pko  = ((lane >> 4) ^ ((frow >> 1) & 3)) * 8;

  PCtx c;
  c.pA = P + (long)b * Sc * Sc + (long)(m0 + wave * 32 + sr) * K + scol;
  c.pB = vt + (long)b * DKc * Sc + (long)(n0 + wave * 16 + sr) * K + scol;
  c.stA = wave * 1024;
  c.stB = wave * 512;
  c.aoff = (wm * 64 + frow) * 32 + pko;
  c.boff = (wn * 64 + frow) * 32 + pko;

  __bf16* B0 = smem;
  __bf16* B1 = smem + 24576;
  __bf16* B2 = smem + 49152;

  // Prologue (FIFO-order-critical): t0 {A0 x2, B0, A1 x2, B1}, t1 same.
  stage16(c.pA, B0 + c.stA);            stage16(c.pA + 16 * K, B0 + c.stA + 512);
  stage16(c.pB, B0 + 16384 + c.stB);
  stage16(c.pA + 32, B0 + 8192 + c.stA); stage16(c.pA + 32 + 16 * K, B0 + 8192 + c.stA + 512);
  stage16(c.pB + 32, B0 + 20480 + c.stB);
  stage16(c.pA + 64, B1 + c.stA);       stage16(c.pA + 64 + 16 * K, B1 + c.stA + 512);
  stage16(c.pB + 64, B1 + 16384 + c.stB);
  stage16(c.pA + 96, B1 + 8192 + c.stA); stage16(c.pA + 96 + 16 * K, B1 + 8192 + c.stA + 512);
  stage16(c.pB + 96, B1 + 20480 + c.stB);

  floatx4 acc[4][4];
  const floatx4 zero = {0.f, 0.f, 0.f, 0.f};
#pragma unroll
  for (int i = 0; i < 4; ++i)
#pragma unroll
    for (int j = 0; j < 4; ++j) acc[i][j] = zero;

#pragma unroll 1
  for (int t = 0; t < 30; t += 3) {
    tile_step_pv<2048, 6, true>(c, t,     B0, B2, acc);
    tile_step_pv<2048, 6, true>(c, t + 1, B1, B0, acc);
    tile_step_pv<2048, 6, true>(c, t + 2, B2, B1, acc);
  }
  tile_step_pv<2048, 6, false>(c, 30, B0, B0, acc);
  tile_step_pv<2048, 0, false>(c, 31, B1, B1, acc);

  // ---- epilogue: direct fp32 store ----
  const int crow0 = (lane >> 4) * 4;
  const int ccol  = lane & 15;
#pragma unroll
  for (int nt = 0; nt < 4; ++nt) {
    int cn = n0 + wn * 64 + nt * 16 + ccol;
#pragma unroll
    for (int mt = 0; mt < 4; ++mt) {
#pragma unroll
      for (int r = 0; r < 4; ++r) {
        int cm_ = m0 + wm * 64 + mt * 16 + crow0 + r;
        out[(long)b * Sc * DKc + (long)cm_ * DKc + cn] = acc[mt][nt][r];
      }
    }
  }
}

// ---------------------------------------------------------------------------
// G GEMM, 64x64 tiles (256 blocks). Gt[m][n] = sum_k WK[m,k]WQ[n,k],
// split operands (3 MFMA), hi/lo output.
// ---------------------------------------------------------------------------
__global__ __launch_bounds__(256) void gemm_g64(
    const __bf16* __restrict__ Ahi, const __bf16* __restrict__ Alo,
    const __bf16* __restrict__ Bhi, const __bf16* __restrict__ Blo,
    __bf16* __restrict__ Chi, __bf16* __restrict__ Clo) {
  constexpr int K = Dc, N = DKc;
  __shared__ __align__(16) char smem[16384];
  __bf16* sAh = (__bf16*)smem;           // [64][32]
  __bf16* sBh = sAh + 64 * 32;
  __bf16* sAl = sBh + 64 * 32;
  __bf16* sBl = sAl + 64 * 32;

  const int wave = threadIdx.x >> 6;
  const int lane = threadIdx.x & 63;
  const int wm   = wave >> 1, wn = wave & 1;
  const int m0   = blockIdx.y * 64;
  const int n0   = blockIdx.x * 64;

  const int sr   = lane >> 2;
  const int sc_  = lane & 3;
  const int scol = (sc_ ^ ((sr >> 1) & 3)) * 8;
  const int frow = lane & 15;
  const int pko  = ((lane >> 4) ^ ((frow >> 1) & 3)) * 8;

  floatx4 acc[2][2];
  const floatx4 zero = {0.f, 0.f, 0.f, 0.f};
#pragma unroll
  for (int i = 0; i < 2; ++i)
#pragma unroll
    for (int j = 0; j < 2; ++j) acc[i][j] = zero;

#pragma unroll 1
  for (int k0 = 0; k0 < K; k0 += 32) {
    const int rb = wave * 16;                       // wave stages 16 rows
    const long ga = (long)(m0 + rb + sr) * K + k0 + scol;
    const long gb = (long)(n0 + rb + sr) * K + k0 + scol;
    stage16(Ahi + ga, sAh + rb * 32);
    stage16(Alo + ga, sAl + rb * 32);
    stage16(Bhi + gb, sBh + rb * 32);
    stage16(Blo + gb, sBl + rb * 32);
    __syncthreads();

    bf16x8 af[2], bfr[2], afl[2], bfl[2];
#pragma unroll
    for (int t = 0; t < 2; ++t) {
      af[t]  = *(const bf16x8*)(sAh + (wm * 32 + t * 16 + frow) * 32 + pko);
      bfr[t] = *(const bf16x8*)(sBh + (wn * 32 + t * 16 + frow) * 32 + pko);
      afl[t] = *(const bf16x8*)(sAl + (wm * 32 + t * 16 + frow) * 32 + pko);
      bfl[t] = *(const bf16x8*)(sBl + (wn * 32 + t * 16 + frow) * 32 + pko);
    }
#pragma unroll
    for (int mt = 0; mt < 2; ++mt)
#pragma unroll
      for (int nt = 0; nt < 2; ++nt) {
        acc[mt][nt] = __builtin_amdgcn_mfma_f32_16x16x32_bf16(af[mt], bfr[nt], acc[mt][nt], 0, 0, 0);
        acc[mt][nt] = __builtin_amdgcn_mfma_f32_16x16x32_bf16(af[mt], bfl[nt], acc[mt][nt], 0, 0, 0);
        acc[mt][nt] = __builtin_amdgcn_mfma_f32_16x16x32_bf16(afl[mt], bfr[nt], acc[mt][nt], 0, 0, 0);
      }
    __syncthreads();
  }

  const int crow0 = (lane >> 4) * 4;
  const int ccol  = lane & 15;
  const int tid   = threadIdx.x;
  __bf16* sT = (__bf16*)smem;            // [64][64] = 8KB
#pragma unroll 1
  for (int pass = 0; pass < 2; ++pass) {
    __syncthreads();
#pragma unroll
    for (int nt = 0; nt < 2; ++nt) {
      int col = wn * 32 + nt * 16 + ccol;
#pragma unroll
      for (int mt = 0; mt < 2; ++mt) {
        int row = wm * 32 + mt * 16 + crow0;
#pragma unroll
        for (int r = 0; r < 4; ++r) {
          float v = acc[mt][nt][r];
          __bf16 h = f2bf(v);
          sT[(row + r) * 64 + col] = pass ? f2bf(v - bf2f(h)) : h;
        }
      }
    }
    __syncthreads();
    __bf16* dst = pass ? Clo : Chi;
#pragma unroll
    for (int c = 0; c < 2; ++c) {
      int flat = c * 2048 + tid * 8;
      int row = flat >> 6, col = flat & 63;
      *(bf16x8*)(dst + (long)(m0 + row) * N + n0 + col) = *(const bf16x8*)(sT + flat);
    }
  }
}

// ---------------------------------------------------------------------------
// Fold 16 q-tile partials -> ffac[b][t][k] = exp(M_t - M_k) / Z_k.
// ---------------------------------------------------------------------------
__global__ __launch_bounds__(256) void softmax_reduce(const float* __restrict__ Pmax,
                                                      const float* __restrict__ Psum,
                                                      float* __restrict__ Ffac) {
  int idx = blockIdx.x * 256 + threadIdx.x;   // b*2048 + k
  int b = idx >> 11, k = idx & (Sc - 1);
  const float* pm = Pmax + (long)b * 16 * Sc + k;
  const float* ps = Psum + (long)b * 16 * Sc + k;
  float M = -3.0e38f;
#pragma unroll
  for (int t = 0; t < 16; ++t) M = fmaxf(M, pm[(long)t * Sc]);
  float S = 0.f;
#pragma unroll
  for (int t = 0; t < 16; ++t)
    S += ps[(long)t * Sc] * __expf(pm[(long)t * Sc] - M);
  float inv = 1.0f / S;
  float* fo = Ffac + (long)b * 16 * Sc + k;
#pragma unroll
  for (int t = 0; t < 16; ++t)
    fo[(long)t * Sc] = __expf(pm[(long)t * Sc] - M) * inv;
}

// ---------------------------------------------------------------------------
extern "C" void kernel_launch(void* const* d_in, const int* in_sizes, int n_in,
                              void* d_out, int out_size, void* d_ws, size_t ws_size,
                              hipStream_t stream) {
  const float* x  = (const float*)d_in[0];
  const float* WQ = (const float*)d_in[1];
  const float* WK = (const float*)d_in[2];
  const float* WV = (const float*)d_in[3];
  float* out = (float*)d_out;
  char* ws = (char*)d_ws;
  const long MB = 1024L * 1024L;

  // Workspace layout (peak ~131 MB).
  __bf16* xhi  = (__bf16*)(ws + 0 * MB);     // 16 MB
  __bf16* xlo  = (__bf16*)(ws + 16 * MB);    // 16 MB
  __bf16* wqhi = (__bf16*)(ws + 32 * MB);    // 2 MB each (element-wise split)
  __bf16* wqlo = (__bf16*)(ws + 34 * MB);
  __bf16* wkhi = (__bf16*)(ws + 36 * MB);
  __bf16* wklo = (__bf16*)(ws + 38 * MB);
  __bf16* wvthi= (__bf16*)(ws + 40 * MB);    // transposed, hi only
  __bf16* gthi = (__bf16*)(ws + 44 * MB);    // 2 MB each: Gt = (WQ WK^T)^T
  __bf16* gtlo = (__bf16*)(ws + 46 * MB);
  __bf16* thi  = (__bf16*)(ws + 48 * MB);    // 16 MB each: T = x*G
  __bf16* tlo  = (__bf16*)(ws + 64 * MB);
  __bf16* vt   = (__bf16*)(ws + 80 * MB);    // 16 MB, [B][DK][S]
  __bf16* P    = (__bf16*)(ws + 96 * MB);    // 32 MB, p = exp(s - M_t), bf16
  float*  pmax = (float*)(ws + 128 * MB);    // [B][16][S] = 512 KB
  float*  psum = (float*)(ws + 129 * MB);
  float*  ffac = (float*)(ws + 130 * MB);    // [B][16][S]

  // 1. casts (float4-vectorized) + WV transpose (one dispatch)
  prep<<<11264, 256, 0, stream>>>(x, xhi, xlo, WQ, wqhi, wqlo, WK, wkhi, wklo,
                                  WV, wvthi);

  // 2. Gt[d][a] = G[a][d]: NT(A=WK, B=WQ), 64x64 tiles -> 256 blocks.
  gemm_g64<<<dim3(16, 16), 256, 0, stream>>>(wkhi, wklo, wqhi, wqlo, gthi, gtlo);

  // 3+4. Fused: T = x*G (blocks 0..255) and Vt = (x*WV)^T (blocks 256..511).
  gemm_tv<<<512, 512, 0, stream>>>(xhi, xlo, gthi, gtlo, thi, tlo, wvthi, vt);

  // 5. S = T*x^T * scale; p + per-128-tile column max/expsum.
  //    128^2 tiles, 64 KB double-buffered -> 2 co-resident blocks/CU.
  gemm_s7<<<dim3(Sc / 128, Sc / 128, Bc), 256, 0, stream>>>(
      thi, tlo, xhi, xlo, P, pmax, psum);

  // 6. partials -> ffac (16 q-tiles)
  softmax_reduce<<<32, 256, 0, stream>>>(pmax, psum, ffac);

  // 7. P <- P .* ffac (elementwise).
  scale_p<<<8192, 256, 0, stream>>>(P, ffac);

  // 8. out = P @ Vt^T -- 1-barrier pipeline.
  gemm_pv4<<<dim3(Sc / 256, DKc / 128, Bc), 512, 0, stream>>>(P, vt, out);
}

// Round 11
// 323.215 us; speedup vs baseline: 1.0650x; 1.0650x over previous
//
#include <hip/hip_runtime.h>

// Problem constants (fixed by the reference): B=4, S=2048, D=DK=1024.
constexpr int Bc  = 4;
constexpr int Sc  = 2048;
constexpr int Dc  = 1024;
constexpr int DKc = 1024;
constexpr long BSc = (long)Bc * Sc;      // 8192 flattened rows of x

typedef __attribute__((ext_vector_type(8))) __bf16 bf16x8;
typedef __attribute__((ext_vector_type(4))) __bf16 bf16x4;
typedef __attribute__((ext_vector_type(4))) float  floatx4;

__device__ inline __bf16 f2bf(float f) {
  unsigned u = __builtin_bit_cast(unsigned, f);
  u = (u + 0x7FFFu + ((u >> 16) & 1u)) >> 16;      // RNE
  unsigned short s = (unsigned short)u;
  return __builtin_bit_cast(__bf16, s);
}
__device__ inline float bf2f(__bf16 h) {
  unsigned u = ((unsigned)__builtin_bit_cast(unsigned short, h)) << 16;
  return __builtin_bit_cast(float, u);
}

// async global->LDS, 16B per lane. lds base must be wave-uniform; HW scatters
// lane i's 16B to ldsbase + i*16.
__device__ inline void stage16(const __bf16* g, __bf16* l) {
  __builtin_amdgcn_global_load_lds(
      (const __attribute__((address_space(1))) unsigned int*)g,
      (__attribute__((address_space(3))) unsigned int*)l, 16, 0, 0);
}

__device__ __forceinline__ void bar_raw() {
  asm volatile("" ::: "memory");
  __builtin_amdgcn_s_barrier();
  asm volatile("" ::: "memory");
}
template <int N>
__device__ __forceinline__ void vmwait() {
  asm volatile("s_waitcnt vmcnt(%0)" :: "n"(N));
  __builtin_amdgcn_sched_barrier(0);
}

// ---------------------------------------------------------------------------
// prep: fp32->bf16 hi/lo splits, float4-vectorized (16B/lane, G13):
// x (8192 blks), WQ (1024), WK (1024); plus WV transpose (1024 blks).
// ---------------------------------------------------------------------------
__global__ __launch_bounds__(256) void prep(
    const float* __restrict__ x,  __bf16* __restrict__ xhi, __bf16* __restrict__ xlo,
    const float* __restrict__ wq, __bf16* __restrict__ qhi, __bf16* __restrict__ qlo,
    const float* __restrict__ wk, __bf16* __restrict__ khi, __bf16* __restrict__ klo,
    const float* __restrict__ wv, __bf16* __restrict__ vthi) {
  __shared__ float tile[32][33];
  long blk = blockIdx.x;
  if (blk >= 10240) {                 // WV transpose: Wt[dk][d] = W[d][dk]
    int t   = (int)(blk - 10240);
    int bx  = t & 31, by = t >> 5;
    int thx = threadIdx.x & 31, thy = threadIdx.x >> 5;   // 32 x 8
    int xI  = bx * 32 + thx, yI = by * 32 + thy;
#pragma unroll
    for (int j = 0; j < 32; j += 8)
      tile[thy + j][thx] = wv[(long)(yI + j) * DKc + xI];
    __syncthreads();
    int xO = by * 32 + thx, yO = bx * 32 + thy;
#pragma unroll
    for (int j = 0; j < 32; j += 8)
      vthi[(long)(yO + j) * Dc + xO] = f2bf(tile[thx][thy + j]);
    return;
  }
  const float* in; __bf16 *hi, *lo; long base;
  if (blk < 8192)      { in = x;  hi = xhi; lo = xlo; base = blk * 1024; }
  else if (blk < 9216) { in = wq; hi = qhi; lo = qlo; base = (blk - 8192) * 1024; }
  else                 { in = wk; hi = khi; lo = klo; base = (blk - 9216) * 1024; }
  long i = base + (long)threadIdx.x * 4;
  float4 f = *(const float4*)(in + i);
  __bf16 h0 = f2bf(f.x), h1 = f2bf(f.y), h2 = f2bf(f.z), h3 = f2bf(f.w);
  bf16x4 hv = {h0, h1, h2, h3};
  bf16x4 lv = {f2bf(f.x - bf2f(h0)), f2bf(f.y - bf2f(h1)),
               f2bf(f.z - bf2f(h2)), f2bf(f.w - bf2f(h3))};
  *(bf16x4*)(hi + i) = hv;
  *(bf16x4*)(lo + i) = lv;
}

// ---------------------------------------------------------------------------
// gemm_s5: S = T x^T (split, 3-MFMA) at 256x256/BK=32, 8 waves (2x4), wave
// tile 128x64, 16x16x32 MFMA. Session-best verified config (R7/R9: ~90 us,
// MfmaUtil ~50%):
//   region 1: SAL issue, af/bfr/bfl reads, phases A+B (64 MFMA).
//   region 2: S2A+S2B issue, afl reads, phase C.
// Single counted vmwait W=6; tails <6,SAL-only> then <0>.
// Do-not-retry (falsified): 32x32 MFMA (R4: breaks chunk-XOR, 6.3M bank
// conflicts); single-buffer in-place (R8: vmwait<0> drain anti-pattern);
// 128^2 co-residency (R10: same-schedule blocks phase-lock, no m114 overlap).
// ---------------------------------------------------------------------------
struct SCtx {
  const __bf16 *pAh, *pAl, *pBh, *pBl;  // per-thread staging src (row+swz col)
  __bf16* lds;
  int stLds;                             // wave*32 rows * 32 elems
  int aoff, boff;                        // frag base offsets (elements)
};

template <int W, bool SAL, bool S2A, bool S2B>
__device__ __forceinline__ void tile_step(const SCtx& c, int t,
                                          floatx4 (&acc)[8][4]) {
  constexpr int K = 1024;
  constexpr int BH = 8192, BL = 16384, AL = 24576;   // region elem offsets
  __bf16* cur = c.lds + (t & 1) * 32768;
  __bf16* oth = c.lds + ((t & 1) ^ 1) * 32768;
  bf16x8 af[8], bfr[4], bfl[4];

  vmwait<W>();
  bar_raw();
  if (SAL) {  // stage Al_{t+1} into other buffer (readers passed bar 1)
    const __bf16* s = c.pAl + (t + 1) * 32;
    stage16(s, oth + AL + c.stLds);
    stage16(s + 16 * K, oth + AL + c.stLds + 512);
  }
#pragma unroll
  for (int mt = 0; mt < 8; ++mt)
    af[mt] = *(const bf16x8*)(cur + c.aoff + mt * 512);
#pragma unroll
  for (int nt = 0; nt < 4; ++nt)
    bfr[nt] = *(const bf16x8*)(cur + BH + c.boff + nt * 512);
#pragma unroll
  for (int nt = 0; nt < 4; ++nt)
    bfl[nt] = *(const bf16x8*)(cur + BL + c.boff + nt * 512);

  // ---- phases A+B in the same region as the reads ----
  __builtin_amdgcn_s_setprio(1);
#pragma unroll
  for (int mt = 0; mt < 8; ++mt)
#pragma unroll
    for (int nt = 0; nt < 4; ++nt)
      acc[mt][nt] = __builtin_amdgcn_mfma_f32_16x16x32_bf16(af[mt], bfr[nt], acc[mt][nt], 0, 0, 0);
#pragma unroll
  for (int mt = 0; mt < 8; ++mt)
#pragma unroll
    for (int nt = 0; nt < 4; ++nt)
      acc[mt][nt] = __builtin_amdgcn_mfma_f32_16x16x32_bf16(af[mt], bfl[nt], acc[mt][nt], 0, 0, 0);
  __builtin_amdgcn_s_setprio(0);

  bar_raw();   // all waves consumed AH/BH/BL -> safe to overwrite
  if (S2A) {   // Ah_{t+2} x2 + Bh_{t+2} #1 into cur
    const __bf16* sa = c.pAh + (t + 2) * 32;
    stage16(sa, cur + c.stLds);
    stage16(sa + 16 * K, cur + c.stLds + 512);
    stage16(c.pBh + (t + 2) * 32, cur + BH + c.stLds);
  }
  if (S2B) {   // Bh_{t+2} #2 + Bl_{t+2} x2
    stage16(c.pBh + (t + 2) * 32 + 16 * K, cur + BH + c.stLds + 512);
    const __bf16* sb = c.pBl + (t + 2) * 32;
    stage16(sb, cur + BL + c.stLds);
    stage16(sb + 16 * K, cur + BL + c.stLds + 512);
  }
  {
    // ---- phase C : acc += Al * Bh (afl reads overlap stage issue) ----
    bf16x8 afl[8];
#pragma unroll
    for (int mt = 0; mt < 8; ++mt)
      afl[mt] = *(const bf16x8*)(cur + AL + c.aoff + mt * 512);
    __builtin_amdgcn_s_setprio(1);
#pragma unroll
    for (int mt = 0; mt < 8; ++mt)
#pragma unroll
      for (int nt = 0; nt < 4; ++nt)
        acc[mt][nt] = __builtin_amdgcn_mfma_f32_16x16x32_bf16(afl[mt], bfr[nt], acc[mt][nt], 0, 0, 0);
    __builtin_amdgcn_s_setprio(0);
  }
}

__global__ __launch_bounds__(512, 2) void gemm_s5(
    const __bf16* __restrict__ thi, const __bf16* __restrict__ tlo,
    const __bf16* __restrict__ xhi, const __bf16* __restrict__ xlo,
    __bf16* __restrict__ P, float* __restrict__ Pmax, float* __restrict__ Psum) {
  __shared__ __align__(16) __bf16 smem[65536];   // 128 KB: 2 x {Ah,Bh,Bl,Al}
  constexpr int K = 1024;
  const int b    = blockIdx.z;
  const int m0   = blockIdx.y * 256;
  const int n0   = blockIdx.x * 256;
  const int wave = threadIdx.x >> 6;
  const int lane = threadIdx.x & 63;
  const int wm   = wave >> 2;            // 0..1
  const int wn   = wave & 3;             // 0..3
  const int sr   = lane >> 2;
  const int scol = ((lane & 3) ^ ((sr >> 1) & 3)) * 8;   // chunk-XOR swizzle
  const int frow = lane & 15;
  const int pko  = ((lane >> 4) ^ ((frow >> 1) & 3)) * 8;

  SCtx c;
  const long batch = (long)Sc * 1024;
  const long ar = (long)(m0 + wave * 32 + sr) * K + scol;
  const long br = (long)(n0 + wave * 32 + sr) * K + scol;
  c.pAh = thi + (long)b * batch + ar;
  c.pAl = tlo + (long)b * batch + ar;
  c.pBh = xhi + (long)b * batch + br;
  c.pBl = xlo + (long)b * batch + br;
  c.lds = smem;
  c.stLds = wave * 1024;
  c.aoff = (wm * 128 + frow) * 32 + pko;
  c.boff = (wn * 64 + frow) * 32 + pko;

  // Prologue: tile0 {Ah,Bh,Bl,Al} + tile1 {Ah,Bh,Bl} (FIFO-order-critical).
  {
    __bf16* b0 = smem;
    __bf16* b1 = smem + 32768;
    stage16(c.pAh, b0 + c.stLds);               stage16(c.pAh + 16 * K, b0 + c.stLds + 512);
    stage16(c.pBh, b0 + 8192 + c.stLds);        stage16(c.pBh + 16 * K, b0 + 8192 + c.stLds + 512);
    stage16(c.pBl, b0 + 16384 + c.stLds);       stage16(c.pBl + 16 * K, b0 + 16384 + c.stLds + 512);
    stage16(c.pAl, b0 + 24576 + c.stLds);       stage16(c.pAl + 16 * K, b0 + 24576 + c.stLds + 512);
    stage16(c.pAh + 32, b1 + c.stLds);          stage16(c.pAh + 32 + 16 * K, b1 + c.stLds + 512);
    stage16(c.pBh + 32, b1 + 8192 + c.stLds);   stage16(c.pBh + 32 + 16 * K, b1 + 8192 + c.stLds + 512);
    stage16(c.pBl + 32, b1 + 16384 + c.stLds);  stage16(c.pBl + 32 + 16 * K, b1 + 16384 + c.stLds + 512);
  }

  floatx4 acc[8][4];
  const floatx4 zero = {0.f, 0.f, 0.f, 0.f};
#pragma unroll
  for (int i = 0; i < 8; ++i)
#pragma unroll
    for (int j = 0; j < 4; ++j) acc[i][j] = zero;

#pragma unroll 1
  for (int t = 0; t < 30; ++t) tile_step<6, true, true, true>(c, t, acc);
  tile_step<6, true, false, false>(c, 30, acc);
  tile_step<0, false, false, false>(c, 31, acc);

  // ---- epilogue: softmax-over-q partials + p = exp(s - M_t) ----
  const int crow0 = (lane >> 4) * 4;
  const int ccol  = lane & 15;
  const int tid   = threadIdx.x;
  constexpr float scale = 0.03125f;
  float* smax = (float*)smem;            // [2][256]
  float* ssum = smax + 512;              // [2][256]

  float cm[4];
#pragma unroll
  for (int nt = 0; nt < 4; ++nt) {
    float mx = -3.0e38f;
#pragma unroll
    for (int mt = 0; mt < 8; ++mt)
#pragma unroll
      for (int r = 0; r < 4; ++r) mx = fmaxf(mx, acc[mt][nt][r] * scale);
    cm[nt] = mx;
  }
#pragma unroll
  for (int off = 16; off <= 32; off <<= 1)
#pragma unroll
    for (int nt = 0; nt < 4; ++nt)
      cm[nt] = fmaxf(cm[nt], __shfl_xor(cm[nt], off, 64));
  __syncthreads();
  if (lane < 16)
#pragma unroll
    for (int nt = 0; nt < 4; ++nt)
      smax[wm * 256 + wn * 64 + nt * 16 + lane] = cm[nt];
  __syncthreads();
  float mfin[4];
#pragma unroll
  for (int nt = 0; nt < 4; ++nt) {
    int cidx = wn * 64 + nt * 16 + ccol;
    mfin[nt] = fmaxf(smax[cidx], smax[256 + cidx]);
  }
  float ps[4];
#pragma unroll
  for (int nt = 0; nt < 4; ++nt) {
    float s = 0.f;
#pragma unroll
    for (int mt = 0; mt < 8; ++mt)
#pragma unroll
      for (int r = 0; r < 4; ++r)
        s += __expf(acc[mt][nt][r] * scale - mfin[nt]);
    ps[nt] = s;
  }
#pragma unroll
  for (int off = 16; off <= 32; off <<= 1)
#pragma unroll
    for (int nt = 0; nt < 4; ++nt) ps[nt] += __shfl_xor(ps[nt], off, 64);
  if (lane < 16)
#pragma unroll
    for (int nt = 0; nt < 4; ++nt)
      ssum[wm * 256 + wn * 64 + nt * 16 + lane] = ps[nt];
  __syncthreads();
  if (tid < 256) {
    long o = ((long)b * 8 + blockIdx.y) * Sc + n0 + tid;
    Pmax[o] = fmaxf(smax[tid], smax[256 + tid]);
    Psum[o] = ssum[tid] + ssum[256 + tid];
  }
  __syncthreads();
  // p -> bf16 via bit4-5 XOR-swizzled LDS round-trip, coalesced 16B stores.
  __bf16* sT = smem;                     // [256][256] = 128 KB
#pragma unroll
  for (int nt = 0; nt < 4; ++nt) {
    int col = wn * 64 + nt * 16 + ccol;
#pragma unroll
    for (int mt = 0; mt < 8; ++mt) {
      int rowb = wm * 128 + mt * 16 + crow0;
#pragma unroll
      for (int r = 0; r < 4; ++r) {
        int row = rowb + r;
        sT[row * 256 + (col ^ (((row >> 2) & 3) << 4))] =
            f2bf(__expf(acc[mt][nt][r] * scale - mfin[nt]));
      }
    }
  }
  __syncthreads();
  __bf16* Pb = P + (long)b * ((long)Sc * Sc);
#pragma unroll
  for (int cc = 0; cc < 16; ++cc) {
    int flat = cc * 4096 + tid * 8;
    int row = flat >> 8, col = flat & 255;
    *(bf16x8*)(Pb + (long)(m0 + row) * Sc + n0 + col) =
        *(const bf16x8*)(sT + row * 256 + (col ^ (((row >> 2) & 3) << 4)));
  }
}

// ---------------------------------------------------------------------------
// t5 body: T = x * G (split, 3-MFMA) at 256x128/BK=32, 512 threads, 8 waves
// as 4x2 (wave tile 64x64). 2 barriers/tile (R6, verified R7). Single vmwait
// W=4; tails <4,SAL> then <0>.
// ---------------------------------------------------------------------------
struct TCtx {
  const __bf16 *pAh, *pAl, *pBh, *pBl;
  __bf16* lds;
  int stA, stB;                          // wave*1024 (A), wave*512 (B)
  int aoff, boff;
};

template <int W, bool SAL, bool S2AB, bool S2B>
__device__ __forceinline__ void tile_step_t(const TCtx& c, int t,
                                            floatx4 (&acc)[4][4]) {
  constexpr int K = 1024;
  constexpr int BH = 8192, BL = 12288, AL = 16384, BUF = 24576;
  __bf16* cur = c.lds + (t & 1) * BUF;
  __bf16* oth = c.lds + ((t & 1) ^ 1) * BUF;
  bf16x8 af[4], bfr[4], bfl[4], afl[4];

  vmwait<W>();
  bar_raw();
  if (SAL) {
    const __bf16* s = c.pAl + (t + 1) * 32;
    stage16(s, oth + AL + c.stA);
    stage16(s + 16 * K, oth + AL + c.stA + 512);
  }
#pragma unroll
  for (int mt = 0; mt < 4; ++mt)
    af[mt] = *(const bf16x8*)(cur + c.aoff + mt * 512);
#pragma unroll
  for (int nt = 0; nt < 4; ++nt)
    bfr[nt] = *(const bf16x8*)(cur + BH + c.boff + nt * 512);
#pragma unroll
  for (int nt = 0; nt < 4; ++nt)
    bfl[nt] = *(const bf16x8*)(cur + BL + c.boff + nt * 512);
#pragma unroll
  for (int mt = 0; mt < 4; ++mt)
    afl[mt] = *(const bf16x8*)(cur + AL + c.aoff + mt * 512);

  __builtin_amdgcn_s_setprio(1);
#pragma unroll
  for (int mt = 0; mt < 4; ++mt)
#pragma unroll
    for (int nt = 0; nt < 4; ++nt)
      acc[mt][nt] = __builtin_amdgcn_mfma_f32_16x16x32_bf16(af[mt], bfr[nt], acc[mt][nt], 0, 0, 0);
#pragma unroll
  for (int mt = 0; mt < 4; ++mt)
#pragma unroll
    for (int nt = 0; nt < 4; ++nt)
      acc[mt][nt] = __builtin_amdgcn_mfma_f32_16x16x32_bf16(af[mt], bfl[nt], acc[mt][nt], 0, 0, 0);
#pragma unroll
  for (int mt = 0; mt < 4; ++mt)
#pragma unroll
    for (int nt = 0; nt < 4; ++nt)
      acc[mt][nt] = __builtin_amdgcn_mfma_f32_16x16x32_bf16(afl[mt], bfr[nt], acc[mt][nt], 0, 0, 0);
  __builtin_amdgcn_s_setprio(0);

  bar_raw();   // all reads consumed -> safe to overwrite cur
  if (S2AB) {
    const __bf16* sa = c.pAh + (t + 2) * 32;
    stage16(sa, cur + c.stA);
    stage16(sa + 16 * K, cur + c.stA + 512);
    stage16(c.pBh + (t + 2) * 32, cur + BH + c.stB);
  }
  if (S2B) stage16(c.pBl + (t + 2) * 32, cur + BL + c.stB);
}

__device__ void t5_body(__bf16* smem,
    const __bf16* __restrict__ xhi, const __bf16* __restrict__ xlo,
    const __bf16* __restrict__ gthi, const __bf16* __restrict__ gtlo,
    __bf16* __restrict__ thi, __bf16* __restrict__ tlo, int bx, int by) {
  constexpr int K = 1024;
  const int m0   = by * 256;
  const int n0   = bx * 128;
  const int wave = threadIdx.x >> 6;
  const int lane = threadIdx.x & 63;
  const int wm   = wave >> 1;            // 0..3
  const int wn   = wave & 1;             // 0..1
  const int sr   = lane >> 2;
  const int scol = ((lane & 3) ^ ((sr >> 1) & 3)) * 8;
  const int frow = lane & 15;
  const int pko  = ((lane >> 4) ^ ((frow >> 1) & 3)) * 8;

  TCtx c;
  const long ar = (long)(m0 + wave * 32 + sr) * K + scol;
  const long br = (long)(n0 + wave * 16 + sr) * K + scol;
  c.pAh = xhi + ar;
  c.pAl = xlo + ar;
  c.pBh = gthi + br;
  c.pBl = gtlo + br;
  c.lds = smem;
  c.stA = wave * 1024;
  c.stB = wave * 512;
  c.aoff = (wm * 64 + frow) * 32 + pko;
  c.boff = (wn * 64 + frow) * 32 + pko;

  // Prologue (FIFO-order-critical): Ah0 x2, Bh0, Bl0, Al0 x2, Ah1 x2, Bh1, Bl1.
  {
    __bf16* b0 = smem;
    __bf16* b1 = smem + 24576;
    stage16(c.pAh, b0 + c.stA);          stage16(c.pAh + 16 * K, b0 + c.stA + 512);
    stage16(c.pBh, b0 + 8192 + c.stB);
    stage16(c.pBl, b0 + 12288 + c.stB);
    stage16(c.pAl, b0 + 16384 + c.stA);  stage16(c.pAl + 16 * K, b0 + 16384 + c.stA + 512);
    stage16(c.pAh + 32, b1 + c.stA);     stage16(c.pAh + 32 + 16 * K, b1 + c.stA + 512);
    stage16(c.pBh + 32, b1 + 8192 + c.stB);
    stage16(c.pBl + 32, b1 + 12288 + c.stB);
  }

  floatx4 acc[4][4];
  const floatx4 zero = {0.f, 0.f, 0.f, 0.f};
#pragma unroll
  for (int i = 0; i < 4; ++i)
#pragma unroll
    for (int j = 0; j < 4; ++j) acc[i][j] = zero;

#pragma unroll 1
  for (int t = 0; t < 30; ++t) tile_step_t<4, true, true, true>(c, t, acc);
  tile_step_t<4, true, false, false>(c, 30, acc);
  tile_step_t<0, false, false, false>(c, 31, acc);

  // ---- epilogue: hi/lo split via XOR-swizzled [256][128] LDS round-trip ----
  const int crow0 = (lane >> 4) * 4;
  const int ccol  = lane & 15;
  const int tid   = threadIdx.x;
  __bf16* sT = smem;                     // 64 KB
#pragma unroll 1
  for (int pass = 0; pass < 2; ++pass) {
    __syncthreads();
#pragma unroll
    for (int nt = 0; nt < 4; ++nt) {
      int col = wn * 64 + nt * 16 + ccol;
#pragma unroll
      for (int mt = 0; mt < 4; ++mt) {
        int rowb = wm * 64 + mt * 16 + crow0;
#pragma unroll
        for (int r = 0; r < 4; ++r) {
          int row = rowb + r;
          float v = acc[mt][nt][r];
          __bf16 h = f2bf(v);
          sT[row * 128 + (col ^ (((row >> 2) & 3) << 4))] =
              pass ? f2bf(v - bf2f(h)) : h;
        }
      }
    }
    __syncthreads();
    __bf16* dst = pass ? tlo : thi;
#pragma unroll
    for (int cc = 0; cc < 8; ++cc) {
      int flat = cc * 4096 + tid * 8;
      int row = flat >> 7, col = flat & 127;
      *(bf16x8*)(dst + (long)(m0 + row) * DKc + n0 + col) =
          *(const bf16x8*)(sT + row * 128 + (col ^ (((row >> 2) & 3) << 4)));
    }
  }
}

// ---------------------------------------------------------------------------
// Shared 2-phase/3-buffer counted-vmcnt NT GEMM step (R6: ONE barrier/tile).
// {vmwait W, bar, 6 stages, 16 reads, 32 MFMA}. Steady W=6; tails
// <6,no-stg> then <0>. Verified R7/R9.
// Buffer regions (elems): A0=0, A1=8192, B0=16384, B1=20480; buffer=24576.
// ---------------------------------------------------------------------------
struct PCtx {
  const __bf16 *pA, *pB;
  int stA, stB;                          // wave*1024 (A), wave*512 (B)
  int aoff, boff;
};

template <int KK, int W, bool STG>
__device__ __forceinline__ void tile_step_pv(const PCtx& c, int t,
                                             __bf16* cur, __bf16* dst,
                                             floatx4 (&acc)[4][4]) {
  vmwait<W>();
  bar_raw();
  if (STG) {
    const __bf16* a = c.pA + (t + 2) * 64;
    stage16(a, dst + c.stA);
    stage16(a + 16 * KK, dst + c.stA + 512);
    stage16(c.pB + (t + 2) * 64, dst + 16384 + c.stB);
    stage16(a + 32, dst + 8192 + c.stA);
    stage16(a + 32 + 16 * KK, dst + 8192 + c.stA + 512);
    stage16(c.pB + (t + 2) * 64 + 32, dst + 20480 + c.stB);
  }
  bf16x8 a0[4], b0[4], a1[4], b1[4];
#pragma unroll
  for (int mt = 0; mt < 4; ++mt)
    a0[mt] = *(const bf16x8*)(cur + c.aoff + mt * 512);
#pragma unroll
  for (int nt = 0; nt < 4; ++nt)
    b0[nt] = *(const bf16x8*)(cur + 16384 + c.boff + nt * 512);
#pragma unroll
  for (int mt = 0; mt < 4; ++mt)
    a1[mt] = *(const bf16x8*)(cur + 8192 + c.aoff + mt * 512);
#pragma unroll
  for (int nt = 0; nt < 4; ++nt)
    b1[nt] = *(const bf16x8*)(cur + 20480 + c.boff + nt * 512);
  __builtin_amdgcn_s_setprio(1);
#pragma unroll
  for (int mt = 0; mt < 4; ++mt)
#pragma unroll
    for (int nt = 0; nt < 4; ++nt)
      acc[mt][nt] = __builtin_amdgcn_mfma_f32_16x16x32_bf16(a0[mt], b0[nt], acc[mt][nt], 0, 0, 0);
#pragma unroll
  for (int mt = 0; mt < 4; ++mt)
#pragma unroll
    for (int nt = 0; nt < 4; ++nt)
      acc[mt][nt] = __builtin_amdgcn_mfma_f32_16x16x32_bf16(a1[mt], b1[nt], acc[mt][nt], 0, 0, 0);
  __builtin_amdgcn_s_setprio(0);
}

// ---------------------------------------------------------------------------
// v4 body: Vt = (x*WV)^T, 1-barrier pipeline (KK=1024, 16 K-tiles).
// Epilogue: transpose via padded LDS [128][VSTR2=264], 16B stores.
// ---------------------------------------------------------------------------
constexpr int VSTR2 = 264;

__device__ void v4_body(__bf16* smem,
    const __bf16* __restrict__ xhi, const __bf16* __restrict__ wvthi,
    __bf16* __restrict__ vt, int bx, int by) {
  constexpr int K = 1024;
  const int m0   = by * 256;             // seq (flattened b*S)
  const int n0   = bx * 128;             // dk
  const int wave = threadIdx.x >> 6;
  const int lane = threadIdx.x & 63;
  const int wm   = wave >> 1;            // 0..3
  const int wn   = wave & 1;             // 0..1
  const int sr   = lane >> 2;
  const int scol = ((lane & 3) ^ ((sr >> 1) & 3)) * 8;
  const int frow = lane & 15;
  const int pko  = ((lane >> 4) ^ ((frow >> 1) & 3)) * 8;

  PCtx c;
  c.pA = xhi + (long)(m0 + wave * 32 + sr) * K + scol;
  c.pB = wvthi + (long)(n0 + wave * 16 + sr) * K + scol;
  c.stA = wave * 1024;
  c.stB = wave * 512;
  c.aoff = (wm * 64 + frow) * 32 + pko;
  c.boff = (wn * 64 + frow) * 32 + pko;

  __bf16* B0 = smem;
  __bf16* B1 = smem + 24576;
  __bf16* B2 = smem + 49152;

  // Prologue (FIFO-order-critical): t0 {A0 x2, B0, A1 x2, B1}, t1 same.
  stage16(c.pA, B0 + c.stA);            stage16(c.pA + 16 * K, B0 + c.stA + 512);
  stage16(c.pB, B0 + 16384 + c.stB);
  stage16(c.pA + 32, B0 + 8192 + c.stA); stage16(c.pA + 32 + 16 * K, B0 + 8192 + c.stA + 512);
  stage16(c.pB + 32, B0 + 20480 + c.stB);
  stage16(c.pA + 64, B1 + c.stA);       stage16(c.pA + 64 + 16 * K, B1 + c.stA + 512);
  stage16(c.pB + 64, B1 + 16384 + c.stB);
  stage16(c.pA + 96, B1 + 8192 + c.stA); stage16(c.pA + 96 + 16 * K, B1 + 8192 + c.stA + 512);
  stage16(c.pB + 96, B1 + 20480 + c.stB);

  floatx4 acc[4][4];
  const floatx4 zero = {0.f, 0.f, 0.f, 0.f};
#pragma unroll
  for (int i = 0; i < 4; ++i)
#pragma unroll
    for (int j = 0; j < 4; ++j) acc[i][j] = zero;

#pragma unroll 1
  for (int t = 0; t < 12; t += 3) {
    tile_step_pv<1024, 6, true>(c, t,     B0, B2, acc);
    tile_step_pv<1024, 6, true>(c, t + 1, B1, B0, acc);
    tile_step_pv<1024, 6, true>(c, t + 2, B2, B1, acc);
  }
  tile_step_pv<1024, 6, true >(c, 12, B0, B2, acc);
  tile_step_pv<1024, 6, true >(c, 13, B1, B0, acc);
  tile_step_pv<1024, 6, false>(c, 14, B2, B2, acc);
  tile_step_pv<1024, 0, false>(c, 15, B0, B0, acc);

  // ---- epilogue: transpose via padded LDS, 16B stores to vt[b][dk][s] ----
  const int crow0 = (lane >> 4) * 4;
  const int ccol  = lane & 15;
  const int tid   = threadIdx.x;
  __syncthreads();
  __bf16* sT = smem;                     // [128][VSTR2]
#pragma unroll
  for (int nt = 0; nt < 4; ++nt) {
    int nl = wn * 64 + nt * 16 + ccol;   // dk-local 0..127
#pragma unroll
    for (int mt = 0; mt < 4; ++mt) {
      int ml = wm * 64 + mt * 16 + crow0;  // seq-local 0..255
#pragma unroll
      for (int r = 0; r < 4; ++r)
        sT[(long)nl * VSTR2 + ml + r] = f2bf(acc[mt][nt][r]);
    }
  }
  __syncthreads();
  const int bb   = m0 >> 11;            // tile fully within one batch
  const int seq0 = m0 & (Sc - 1);
  __bf16* dst = vt + (long)bb * DKc * Sc + seq0;
#pragma unroll
  for (int cc = 0; cc < 8; ++cc) {
    int flat = cc * 4096 + tid * 8;     // logical 128x256; 16B per thread
    int row = flat >> 8, col = flat & 255;
    *(bf16x8*)(dst + (long)(n0 + row) * Sc + col) =
        *(const bf16x8*)(sT + (long)row * VSTR2 + col);
  }
}

// ---------------------------------------------------------------------------
// gemm_tv: fused T-GEMM (blocks 0..255) + V-GEMM (blocks 256..511).
// Verified R9 (tail overlap win).
// ---------------------------------------------------------------------------
__global__ __launch_bounds__(512, 2) void gemm_tv(
    const __bf16* __restrict__ xhi, const __bf16* __restrict__ xlo,
    const __bf16* __restrict__ gthi, const __bf16* __restrict__ gtlo,
    __bf16* __restrict__ thi, __bf16* __restrict__ tlo,
    const __bf16* __restrict__ wvthi, __bf16* __restrict__ vt) {
  __shared__ __align__(16) __bf16 smem[73728];   // 144 KB (v-part max)
  int bid = blockIdx.x;
  if (bid < 256) {
    t5_body(smem, xhi, xlo, gthi, gtlo, thi, tlo, bid & 7, bid >> 3);
  } else {
    bid -= 256;
    v4_body(smem, xhi, wvthi, vt, bid & 7, bid >> 3);
  }
}

// ---------------------------------------------------------------------------
// scale_p: P <- P .* ffac[b][t(q)][k]  (elementwise, memory-bound).
// q-tiles are 256 rows (gemm_s5).
// ---------------------------------------------------------------------------
__global__ __launch_bounds__(256) void scale_p(__bf16* __restrict__ P,
                                               const float* __restrict__ ffac) {
  long i8 = (long)blockIdx.x * 256 + threadIdx.x;
  long base = i8 * 8;
  int k = (int)(base & (Sc - 1));
  int q = (int)((base >> 11) & (Sc - 1));
  int b = (int)(base >> 22);
  int t = q >> 8;                         // 256-row q-tiles
  const float* f = ffac + (((long)b * 8 + t) << 11) + k;
  float4 f0 = *(const float4*)f;
  float4 f1 = *(const float4*)(f + 4);
  bf16x8 p = *(const bf16x8*)(P + base);
  bf16x8 o;
  o[0] = f2bf(bf2f(p[0]) * f0.x);
  o[1] = f2bf(bf2f(p[1]) * f0.y);
  o[2] = f2bf(bf2f(p[2]) * f0.z);
  o[3] = f2bf(bf2f(p[3]) * f0.w);
  o[4] = f2bf(bf2f(p[4]) * f1.x);
  o[5] = f2bf(bf2f(p[5]) * f1.y);
  o[6] = f2bf(bf2f(p[6]) * f1.z);
  o[7] = f2bf(bf2f(p[7]) * f1.w);
  *(bf16x8*)(P + base) = o;
}

// ---------------------------------------------------------------------------
// gemm_pv4: out = attn @ Vt^T, plain NT GEMM (1-barrier pipeline). Verified R7.
// ---------------------------------------------------------------------------
__global__ __launch_bounds__(512, 2) void gemm_pv4(
    const __bf16* __restrict__ P, const __bf16* __restrict__ vt,
    float* __restrict__ out) {
  __shared__ __align__(16) __bf16 smem[73728];   // 144 KB = 3 x 48 KB buffers
  constexpr int K = 2048;
  const int b    = blockIdx.z;
  const int m0   = blockIdx.x * 256;     // q   (x=q: P-panel XCD locality)
  const int n0   = blockIdx.y * 128;     // dk
  const int wave = threadIdx.x >> 6;
  const int lane = threadIdx.x & 63;
  const int wm   = wave >> 1;            // 0..3
  const int wn   = wave & 1;             // 0..1
  const int sr   = lane >> 2;
  const int scol = ((lane & 3) ^ ((sr >> 1) & 3)) * 8;
  const int frow = lane & 15;
  const int pko  = ((lane >> 4) ^ ((frow >> 1) & 3)) * 8;

  PCtx c;
  c.pA = P + (long)b * Sc * Sc + (long)(m0 + wave * 32 + sr) * K + scol;
  c.pB = vt + (long)b * DKc * Sc + (long)(n0 + wave * 16 + sr) * K + scol;
  c.stA = wave * 1024;
  c.stB = wave * 512;
  c.aoff = (wm * 64 + frow) * 32 + pko;
  c.boff = (wn * 64 + frow) * 32 + pko;

  __bf16* B0 = smem;
  __bf16* B1 = smem + 24576;
  __bf16* B2 = smem + 49152;

  // Prologue (FIFO-order-critical): t0 {A0 x2, B0, A1 x2, B1}, t1 same.
  stage16(c.pA, B0 + c.stA);            stage16(c.pA + 16 * K, B0 + c.stA + 512);
  stage16(c.pB, B0 + 16384 + c.stB);
  stage16(c.pA + 32, B0 + 8192 + c.stA); stage16(c.pA + 32 + 16 * K, B0 + 8192 + c.stA + 512);
  stage16(c.pB + 32, B0 + 20480 + c.stB);
  stage16(c.pA + 64, B1 + c.stA);       stage16(c.pA + 64 + 16 * K, B1 + c.stA + 512);
  stage16(c.pB + 64, B1 + 16384 + c.stB);
  stage16(c.pA + 96, B1 + 8192 + c.stA); stage16(c.pA + 96 + 16 * K, B1 + 8192 + c.stA + 512);
  stage16(c.pB + 96, B1 + 20480 + c.stB);

  floatx4 acc[4][4];
  const floatx4 zero = {0.f, 0.f, 0.f, 0.f};
#pragma unroll
  for (int i = 0; i < 4; ++i)
#pragma unroll
    for (int j = 0; j < 4; ++j) acc[i][j] = zero;

#pragma unroll 1
  for (int t = 0; t < 30; t += 3) {
    tile_step_pv<2048, 6, true>(c, t,     B0, B2, acc);
    tile_step_pv<2048, 6, true>(c, t + 1, B1, B0, acc);
    tile_step_pv<2048, 6, true>(c, t + 2, B2, B1, acc);
  }
  tile_step_pv<2048, 6, false>(c, 30, B0, B0, acc);
  tile_step_pv<2048, 0, false>(c, 31, B1, B1, acc);

  // ---- epilogue: direct fp32 store ----
  const int crow0 = (lane >> 4) * 4;
  const int ccol  = lane & 15;
#pragma unroll
  for (int nt = 0; nt < 4; ++nt) {
    int cn = n0 + wn * 64 + nt * 16 + ccol;
#pragma unroll
    for (int mt = 0; mt < 4; ++mt) {
#pragma unroll
      for (int r = 0; r < 4; ++r) {
        int cm_ = m0 + wm * 64 + mt * 16 + crow0 + r;
        out[(long)b * Sc * DKc + (long)cm_ * DKc + cn] = acc[mt][nt][r];
      }
    }
  }
}

// ---------------------------------------------------------------------------
// G GEMM, 64x64 tiles (256 blocks). Gt[m][n] = sum_k WK[m,k]WQ[n,k],
// split operands (3 MFMA), hi/lo output.
// ---------------------------------------------------------------------------
__global__ __launch_bounds__(256) void gemm_g64(
    const __bf16* __restrict__ Ahi, const __bf16* __restrict__ Alo,
    const __bf16* __restrict__ Bhi, const __bf16* __restrict__ Blo,
    __bf16* __restrict__ Chi, __bf16* __restrict__ Clo) {
  constexpr int K = Dc, N = DKc;
  __shared__ __align__(16) char smem[16384];
  __bf16* sAh = (__bf16*)smem;           // [64][32]
  __bf16* sBh = sAh + 64 * 32;
  __bf16* sAl = sBh + 64 * 32;
  __bf16* sBl = sAl + 64 * 32;

  const int wave = threadIdx.x >> 6;
  const int lane = threadIdx.x & 63;
  const int wm   = wave >> 1, wn = wave & 1;
  const int m0   = blockIdx.y * 64;
  const int n0   = blockIdx.x * 64;

  const int sr   = lane >> 2;
  const int sc_  = lane & 3;
  const int scol = (sc_ ^ ((sr >> 1) & 3)) * 8;
  const int frow = lane & 15;
  const int pko  = ((lane >> 4) ^ ((frow >> 1) & 3)) * 8;

  floatx4 acc[2][2];
  const floatx4 zero = {0.f, 0.f, 0.f, 0.f};
#pragma unroll
  for (int i = 0; i < 2; ++i)
#pragma unroll
    for (int j = 0; j < 2; ++j) acc[i][j] = zero;

#pragma unroll 1
  for (int k0 = 0; k0 < K; k0 += 32) {
    const int rb = wave * 16;                       // wave stages 16 rows
    const long ga = (long)(m0 + rb + sr) * K + k0 + scol;
    const long gb = (long)(n0 + rb + sr) * K + k0 + scol;
    stage16(Ahi + ga, sAh + rb * 32);
    stage16(Alo + ga, sAl + rb * 32);
    stage16(Bhi + gb, sBh + rb * 32);
    stage16(Blo + gb, sBl + rb * 32);
    __syncthreads();

    bf16x8 af[2], bfr[2], afl[2], bfl[2];
#pragma unroll
    for (int t = 0; t < 2; ++t) {
      af[t]  = *(const bf16x8*)(sAh + (wm * 32 + t * 16 + frow) * 32 + pko);
      bfr[t] = *(const bf16x8*)(sBh + (wn * 32 + t * 16 + frow) * 32 + pko);
      afl[t] = *(const bf16x8*)(sAl + (wm * 32 + t * 16 + frow) * 32 + pko);
      bfl[t] = *(const bf16x8*)(sBl + (wn * 32 + t * 16 + frow) * 32 + pko);
    }
#pragma unroll
    for (int mt = 0; mt < 2; ++mt)
#pragma unroll
      for (int nt = 0; nt < 2; ++nt) {
        acc[mt][nt] = __builtin_amdgcn_mfma_f32_16x16x32_bf16(af[mt], bfr[nt], acc[mt][nt], 0, 0, 0);
        acc[mt][nt] = __builtin_amdgcn_mfma_f32_16x16x32_bf16(af[mt], bfl[nt], acc[mt][nt], 0, 0, 0);
        acc[mt][nt] = __builtin_amdgcn_mfma_f32_16x16x32_bf16(afl[mt], bfr[nt], acc[mt][nt], 0, 0, 0);
      }
    __syncthreads();
  }

  const int crow0 = (lane >> 4) * 4;
  const int ccol  = lane & 15;
  const int tid   = threadIdx.x;
  __bf16* sT = (__bf16*)smem;            // [64][64] = 8KB
#pragma unroll 1
  for (int pass = 0; pass < 2; ++pass) {
    __syncthreads();
#pragma unroll
    for (int nt = 0; nt < 2; ++nt) {
      int col = wn * 32 + nt * 16 + ccol;
#pragma unroll
      for (int mt = 0; mt < 2; ++mt) {
        int row = wm * 32 + mt * 16 + crow0;
#pragma unroll
        for (int r = 0; r < 4; ++r) {
          float v = acc[mt][nt][r];
          __bf16 h = f2bf(v);
          sT[(row + r) * 64 + col] = pass ? f2bf(v - bf2f(h)) : h;
        }
      }
    }
    __syncthreads();
    __bf16* dst = pass ? Clo : Chi;
#pragma unroll
    for (int c = 0; c < 2; ++c) {
      int flat = c * 2048 + tid * 8;
      int row = flat >> 6, col = flat & 63;
      *(bf16x8*)(dst + (long)(m0 + row) * N + n0 + col) = *(const bf16x8*)(sT + flat);
    }
  }
}

// ---------------------------------------------------------------------------
// Fold 8 q-tile partials -> ffac[b][t][k] = exp(M_t - M_k) / Z_k.
// ---------------------------------------------------------------------------
__global__ __launch_bounds__(256) void softmax_reduce(const float* __restrict__ Pmax,
                                                      const float* __restrict__ Psum,
                                                      float* __restrict__ Ffac) {
  int idx = blockIdx.x * 256 + threadIdx.x;   // b*2048 + k
  int b = idx >> 11, k = idx & (Sc - 1);
  const float* pm = Pmax + (long)b * 8 * Sc + k;
  const float* ps = Psum + (long)b * 8 * Sc + k;
  float M = -3.0e38f;
#pragma unroll
  for (int t = 0; t < 8; ++t) M = fmaxf(M, pm[(long)t * Sc]);
  float S = 0.f;
#pragma unroll
  for (int t = 0; t < 8; ++t)
    S += ps[(long)t * Sc] * __expf(pm[(long)t * Sc] - M);
  float inv = 1.0f / S;
  float* fo = Ffac + (long)b * 8 * Sc + k;
#pragma unroll
  for (int t = 0; t < 8; ++t)
    fo[(long)t * Sc] = __expf(pm[(long)t * Sc] - M) * inv;
}

// ---------------------------------------------------------------------------
extern "C" void kernel_launch(void* const* d_in, const int* in_sizes, int n_in,
                              void* d_out, int out_size, void* d_ws, size_t ws_size,
                              hipStream_t stream) {
  const float* x  = (const float*)d_in[0];
  const float* WQ = (const float*)d_in[1];
  const float* WK = (const float*)d_in[2];
  const float* WV = (const float*)d_in[3];
  float* out = (float*)d_out;
  char* ws = (char*)d_ws;
  const long MB = 1024L * 1024L;

  // Workspace layout (peak ~131 MB).
  __bf16* xhi  = (__bf16*)(ws + 0 * MB);     // 16 MB
  __bf16* xlo  = (__bf16*)(ws + 16 * MB);    // 16 MB
  __bf16* wqhi = (__bf16*)(ws + 32 * MB);    // 2 MB each (element-wise split)
  __bf16* wqlo = (__bf16*)(ws + 34 * MB);
  __bf16* wkhi = (__bf16*)(ws + 36 * MB);
  __bf16* wklo = (__bf16*)(ws + 38 * MB);
  __bf16* wvthi= (__bf16*)(ws + 40 * MB);    // transposed, hi only
  __bf16* gthi = (__bf16*)(ws + 44 * MB);    // 2 MB each: Gt = (WQ WK^T)^T
  __bf16* gtlo = (__bf16*)(ws + 46 * MB);
  __bf16* thi  = (__bf16*)(ws + 48 * MB);    // 16 MB each: T = x*G
  __bf16* tlo  = (__bf16*)(ws + 64 * MB);
  __bf16* vt   = (__bf16*)(ws + 80 * MB);    // 16 MB, [B][DK][S]
  __bf16* P    = (__bf16*)(ws + 96 * MB);    // 32 MB, p = exp(s - M_t), bf16
  float*  pmax = (float*)(ws + 128 * MB);    // [B][8][S]
  float*  psum = (float*)(ws + 129 * MB);
  float*  ffac = (float*)(ws + 130 * MB);    // [B][8][S]

  // 1. casts (float4-vectorized) + WV transpose (one dispatch)
  prep<<<11264, 256, 0, stream>>>(x, xhi, xlo, WQ, wqhi, wqlo, WK, wkhi, wklo,
                                  WV, wvthi);

  // 2. Gt[d][a] = G[a][d]: NT(A=WK, B=WQ), 64x64 tiles -> 256 blocks.
  gemm_g64<<<dim3(16, 16), 256, 0, stream>>>(wkhi, wklo, wqhi, wqlo, gthi, gtlo);

  // 3+4. Fused: T = x*G (blocks 0..255) and Vt = (x*WV)^T (blocks 256..511).
  gemm_tv<<<512, 512, 0, stream>>>(xhi, xlo, gthi, gtlo, thi, tlo, wvthi, vt);

  // 5. S = T*x^T * scale; emits p (bf16) + per-256-tile column max/expsum.
  gemm_s5<<<dim3(Sc / 256, Sc / 256, Bc), 512, 0, stream>>>(
      thi, tlo, xhi, xlo, P, pmax, psum);

  // 6. partials -> ffac (8 q-tiles)
  softmax_reduce<<<32, 256, 0, stream>>>(pmax, psum, ffac);

  // 7. P <- P .* ffac (elementwise).
  scale_p<<<8192, 256, 0, stream>>>(P, ffac);

  // 8. out = P @ Vt^T -- 1-barrier pipeline.
  gemm_pv4<<<dim3(Sc / 256, DKc / 128, Bc), 512, 0, stream>>>(P, vt, out);
}

// Round 12
// 316.771 us; speedup vs baseline: 1.0867x; 1.0203x over previous
//
#include <hip/hip_runtime.h>

// Problem constants (fixed by the reference): B=4, S=2048, D=DK=1024.
constexpr int Bc  = 4;
constexpr int Sc  = 2048;
constexpr int Dc  = 1024;
constexpr int DKc = 1024;
constexpr long BSc = (long)Bc * Sc;      // 8192 flattened rows of x

typedef __attribute__((ext_vector_type(8))) __bf16 bf16x8;
typedef __attribute__((ext_vector_type(4))) __bf16 bf16x4;
typedef __attribute__((ext_vector_type(4))) float  floatx4;

__device__ inline __bf16 f2bf(float f) {
  unsigned u = __builtin_bit_cast(unsigned, f);
  u = (u + 0x7FFFu + ((u >> 16) & 1u)) >> 16;      // RNE
  unsigned short s = (unsigned short)u;
  return __builtin_bit_cast(__bf16, s);
}
__device__ inline float bf2f(__bf16 h) {
  unsigned u = ((unsigned)__builtin_bit_cast(unsigned short, h)) << 16;
  return __builtin_bit_cast(float, u);
}

// async global->LDS, 16B per lane. lds base must be wave-uniform; HW scatters
// lane i's 16B to ldsbase + i*16.
__device__ inline void stage16(const __bf16* g, __bf16* l) {
  __builtin_amdgcn_global_load_lds(
      (const __attribute__((address_space(1))) unsigned int*)g,
      (__attribute__((address_space(3))) unsigned int*)l, 16, 0, 0);
}

__device__ __forceinline__ void bar_raw() {
  asm volatile("" ::: "memory");
  __builtin_amdgcn_s_barrier();
  asm volatile("" ::: "memory");
}
template <int N>
__device__ __forceinline__ void vmwait() {
  asm volatile("s_waitcnt vmcnt(%0)" :: "n"(N));
  __builtin_amdgcn_sched_barrier(0);
}

// ---------------------------------------------------------------------------
// prep: fp32->bf16 hi/lo splits, float4-vectorized (16B/lane, G13):
// x (8192 blks), WQ (1024), WK (1024); plus WV transpose (1024 blks).
// ---------------------------------------------------------------------------
__global__ __launch_bounds__(256) void prep(
    const float* __restrict__ x,  __bf16* __restrict__ xhi, __bf16* __restrict__ xlo,
    const float* __restrict__ wq, __bf16* __restrict__ qhi, __bf16* __restrict__ qlo,
    const float* __restrict__ wk, __bf16* __restrict__ khi, __bf16* __restrict__ klo,
    const float* __restrict__ wv, __bf16* __restrict__ vthi) {
  __shared__ float tile[32][33];
  long blk = blockIdx.x;
  if (blk >= 10240) {                 // WV transpose: Wt[dk][d] = W[d][dk]
    int t   = (int)(blk - 10240);
    int bx  = t & 31, by = t >> 5;
    int thx = threadIdx.x & 31, thy = threadIdx.x >> 5;   // 32 x 8
    int xI  = bx * 32 + thx, yI = by * 32 + thy;
#pragma unroll
    for (int j = 0; j < 32; j += 8)
      tile[thy + j][thx] = wv[(long)(yI + j) * DKc + xI];
    __syncthreads();
    int xO = by * 32 + thx, yO = bx * 32 + thy;
#pragma unroll
    for (int j = 0; j < 32; j += 8)
      vthi[(long)(yO + j) * Dc + xO] = f2bf(tile[thx][thy + j]);
    return;
  }
  const float* in; __bf16 *hi, *lo; long base;
  if (blk < 8192)      { in = x;  hi = xhi; lo = xlo; base = blk * 1024; }
  else if (blk < 9216) { in = wq; hi = qhi; lo = qlo; base = (blk - 8192) * 1024; }
  else                 { in = wk; hi = khi; lo = klo; base = (blk - 9216) * 1024; }
  long i = base + (long)threadIdx.x * 4;
  float4 f = *(const float4*)(in + i);
  __bf16 h0 = f2bf(f.x), h1 = f2bf(f.y), h2 = f2bf(f.z), h3 = f2bf(f.w);
  bf16x4 hv = {h0, h1, h2, h3};
  bf16x4 lv = {f2bf(f.x - bf2f(h0)), f2bf(f.y - bf2f(h1)),
               f2bf(f.z - bf2f(h2)), f2bf(f.w - bf2f(h3))};
  *(bf16x4*)(hi + i) = hv;
  *(bf16x4*)(lo + i) = lv;
}

// ---------------------------------------------------------------------------
// gemm_s5: S = T x^T (split, 3-MFMA) at 256x256/BK=32, 8 waves (2x4), wave
// tile 128x64, 16x16x32 MFMA. Session-best verified config (R7/R9/R11:
// ~90 us, MfmaUtil ~50%):
//   region 1: SAL issue, af/bfr/bfl reads, phases A+B (64 MFMA).
//   region 2: S2A+S2B issue, afl reads, phase C.
// Single counted vmwait W=6; tails <6,SAL-only> then <0>.
// Do-not-retry (falsified): 32x32 MFMA (R4); single-buffer in-place (R8);
// 128^2 co-residency (R10).
// ---------------------------------------------------------------------------
struct SCtx {
  const __bf16 *pAh, *pAl, *pBh, *pBl;  // per-thread staging src (row+swz col)
  __bf16* lds;
  int stLds;                             // wave*32 rows * 32 elems
  int aoff, boff;                        // frag base offsets (elements)
};

template <int W, bool SAL, bool S2A, bool S2B>
__device__ __forceinline__ void tile_step(const SCtx& c, int t,
                                          floatx4 (&acc)[8][4]) {
  constexpr int K = 1024;
  constexpr int BH = 8192, BL = 16384, AL = 24576;   // region elem offsets
  __bf16* cur = c.lds + (t & 1) * 32768;
  __bf16* oth = c.lds + ((t & 1) ^ 1) * 32768;
  bf16x8 af[8], bfr[4], bfl[4];

  vmwait<W>();
  bar_raw();
  if (SAL) {  // stage Al_{t+1} into other buffer (readers passed bar 1)
    const __bf16* s = c.pAl + (t + 1) * 32;
    stage16(s, oth + AL + c.stLds);
    stage16(s + 16 * K, oth + AL + c.stLds + 512);
  }
#pragma unroll
  for (int mt = 0; mt < 8; ++mt)
    af[mt] = *(const bf16x8*)(cur + c.aoff + mt * 512);
#pragma unroll
  for (int nt = 0; nt < 4; ++nt)
    bfr[nt] = *(const bf16x8*)(cur + BH + c.boff + nt * 512);
#pragma unroll
  for (int nt = 0; nt < 4; ++nt)
    bfl[nt] = *(const bf16x8*)(cur + BL + c.boff + nt * 512);

  // ---- phases A+B in the same region as the reads ----
  __builtin_amdgcn_s_setprio(1);
#pragma unroll
  for (int mt = 0; mt < 8; ++mt)
#pragma unroll
    for (int nt = 0; nt < 4; ++nt)
      acc[mt][nt] = __builtin_amdgcn_mfma_f32_16x16x32_bf16(af[mt], bfr[nt], acc[mt][nt], 0, 0, 0);
#pragma unroll
  for (int mt = 0; mt < 8; ++mt)
#pragma unroll
    for (int nt = 0; nt < 4; ++nt)
      acc[mt][nt] = __builtin_amdgcn_mfma_f32_16x16x32_bf16(af[mt], bfl[nt], acc[mt][nt], 0, 0, 0);
  __builtin_amdgcn_s_setprio(0);

  bar_raw();   // all waves consumed AH/BH/BL -> safe to overwrite
  if (S2A) {   // Ah_{t+2} x2 + Bh_{t+2} #1 into cur
    const __bf16* sa = c.pAh + (t + 2) * 32;
    stage16(sa, cur + c.stLds);
    stage16(sa + 16 * K, cur + c.stLds + 512);
    stage16(c.pBh + (t + 2) * 32, cur + BH + c.stLds);
  }
  if (S2B) {   // Bh_{t+2} #2 + Bl_{t+2} x2
    stage16(c.pBh + (t + 2) * 32 + 16 * K, cur + BH + c.stLds + 512);
    const __bf16* sb = c.pBl + (t + 2) * 32;
    stage16(sb, cur + BL + c.stLds);
    stage16(sb + 16 * K, cur + BL + c.stLds + 512);
  }
  {
    // ---- phase C : acc += Al * Bh (afl reads overlap stage issue) ----
    bf16x8 afl[8];
#pragma unroll
    for (int mt = 0; mt < 8; ++mt)
      afl[mt] = *(const bf16x8*)(cur + AL + c.aoff + mt * 512);
    __builtin_amdgcn_s_setprio(1);
#pragma unroll
    for (int mt = 0; mt < 8; ++mt)
#pragma unroll
      for (int nt = 0; nt < 4; ++nt)
        acc[mt][nt] = __builtin_amdgcn_mfma_f32_16x16x32_bf16(afl[mt], bfr[nt], acc[mt][nt], 0, 0, 0);
    __builtin_amdgcn_s_setprio(0);
  }
}

__global__ __launch_bounds__(512, 2) void gemm_s5(
    const __bf16* __restrict__ thi, const __bf16* __restrict__ tlo,
    const __bf16* __restrict__ xhi, const __bf16* __restrict__ xlo,
    __bf16* __restrict__ P, float* __restrict__ Pmax, float* __restrict__ Psum) {
  __shared__ __align__(16) __bf16 smem[65536];   // 128 KB: 2 x {Ah,Bh,Bl,Al}
  constexpr int K = 1024;
  const int b    = blockIdx.z;
  const int m0   = blockIdx.y * 256;
  const int n0   = blockIdx.x * 256;
  const int wave = threadIdx.x >> 6;
  const int lane = threadIdx.x & 63;
  const int wm   = wave >> 2;            // 0..1
  const int wn   = wave & 3;             // 0..3
  const int sr   = lane >> 2;
  const int scol = ((lane & 3) ^ ((sr >> 1) & 3)) * 8;   // chunk-XOR swizzle
  const int frow = lane & 15;
  const int pko  = ((lane >> 4) ^ ((frow >> 1) & 3)) * 8;

  SCtx c;
  const long batch = (long)Sc * 1024;
  const long ar = (long)(m0 + wave * 32 + sr) * K + scol;
  const long br = (long)(n0 + wave * 32 + sr) * K + scol;
  c.pAh = thi + (long)b * batch + ar;
  c.pAl = tlo + (long)b * batch + ar;
  c.pBh = xhi + (long)b * batch + br;
  c.pBl = xlo + (long)b * batch + br;
  c.lds = smem;
  c.stLds = wave * 1024;
  c.aoff = (wm * 128 + frow) * 32 + pko;
  c.boff = (wn * 64 + frow) * 32 + pko;

  // Prologue: tile0 {Ah,Bh,Bl,Al} + tile1 {Ah,Bh,Bl} (FIFO-order-critical).
  {
    __bf16* b0 = smem;
    __bf16* b1 = smem + 32768;
    stage16(c.pAh, b0 + c.stLds);               stage16(c.pAh + 16 * K, b0 + c.stLds + 512);
    stage16(c.pBh, b0 + 8192 + c.stLds);        stage16(c.pBh + 16 * K, b0 + 8192 + c.stLds + 512);
    stage16(c.pBl, b0 + 16384 + c.stLds);       stage16(c.pBl + 16 * K, b0 + 16384 + c.stLds + 512);
    stage16(c.pAl, b0 + 24576 + c.stLds);       stage16(c.pAl + 16 * K, b0 + 24576 + c.stLds + 512);
    stage16(c.pAh + 32, b1 + c.stLds);          stage16(c.pAh + 32 + 16 * K, b1 + c.stLds + 512);
    stage16(c.pBh + 32, b1 + 8192 + c.stLds);   stage16(c.pBh + 32 + 16 * K, b1 + 8192 + c.stLds + 512);
    stage16(c.pBl + 32, b1 + 16384 + c.stLds);  stage16(c.pBl + 32 + 16 * K, b1 + 16384 + c.stLds + 512);
  }

  floatx4 acc[8][4];
  const floatx4 zero = {0.f, 0.f, 0.f, 0.f};
#pragma unroll
  for (int i = 0; i < 8; ++i)
#pragma unroll
    for (int j = 0; j < 4; ++j) acc[i][j] = zero;

#pragma unroll 1
  for (int t = 0; t < 30; ++t) tile_step<6, true, true, true>(c, t, acc);
  tile_step<6, true, false, false>(c, 30, acc);
  tile_step<0, false, false, false>(c, 31, acc);

  // ---- epilogue: softmax-over-q partials + p = exp(s - M_t) ----
  const int crow0 = (lane >> 4) * 4;
  const int ccol  = lane & 15;
  const int tid   = threadIdx.x;
  constexpr float scale = 0.03125f;
  float* smax = (float*)smem;            // [2][256]
  float* ssum = smax + 512;              // [2][256]

  float cm[4];
#pragma unroll
  for (int nt = 0; nt < 4; ++nt) {
    float mx = -3.0e38f;
#pragma unroll
    for (int mt = 0; mt < 8; ++mt)
#pragma unroll
      for (int r = 0; r < 4; ++r) mx = fmaxf(mx, acc[mt][nt][r] * scale);
    cm[nt] = mx;
  }
#pragma unroll
  for (int off = 16; off <= 32; off <<= 1)
#pragma unroll
    for (int nt = 0; nt < 4; ++nt)
      cm[nt] = fmaxf(cm[nt], __shfl_xor(cm[nt], off, 64));
  __syncthreads();
  if (lane < 16)
#pragma unroll
    for (int nt = 0; nt < 4; ++nt)
      smax[wm * 256 + wn * 64 + nt * 16 + lane] = cm[nt];
  __syncthreads();
  float mfin[4];
#pragma unroll
  for (int nt = 0; nt < 4; ++nt) {
    int cidx = wn * 64 + nt * 16 + ccol;
    mfin[nt] = fmaxf(smax[cidx], smax[256 + cidx]);
  }
  float ps[4];
#pragma unroll
  for (int nt = 0; nt < 4; ++nt) {
    float s = 0.f;
#pragma unroll
    for (int mt = 0; mt < 8; ++mt)
#pragma unroll
      for (int r = 0; r < 4; ++r)
        s += __expf(acc[mt][nt][r] * scale - mfin[nt]);
    ps[nt] = s;
  }
#pragma unroll
  for (int off = 16; off <= 32; off <<= 1)
#pragma unroll
    for (int nt = 0; nt < 4; ++nt) ps[nt] += __shfl_xor(ps[nt], off, 64);
  if (lane < 16)
#pragma unroll
    for (int nt = 0; nt < 4; ++nt)
      ssum[wm * 256 + wn * 64 + nt * 16 + lane] = ps[nt];
  __syncthreads();
  if (tid < 256) {
    long o = ((long)b * 8 + blockIdx.y) * Sc + n0 + tid;
    Pmax[o] = fmaxf(smax[tid], smax[256 + tid]);
    Psum[o] = ssum[tid] + ssum[256 + tid];
  }
  __syncthreads();
  // p -> bf16 via bit4-5 XOR-swizzled LDS round-trip, coalesced 16B stores.
  __bf16* sT = smem;                     // [256][256] = 128 KB
#pragma unroll
  for (int nt = 0; nt < 4; ++nt) {
    int col = wn * 64 + nt * 16 + ccol;
#pragma unroll
    for (int mt = 0; mt < 8; ++mt) {
      int rowb = wm * 128 + mt * 16 + crow0;
#pragma unroll
      for (int r = 0; r < 4; ++r) {
        int row = rowb + r;
        sT[row * 256 + (col ^ (((row >> 2) & 3) << 4))] =
            f2bf(__expf(acc[mt][nt][r] * scale - mfin[nt]));
      }
    }
  }
  __syncthreads();
  __bf16* Pb = P + (long)b * ((long)Sc * Sc);
#pragma unroll
  for (int cc = 0; cc < 16; ++cc) {
    int flat = cc * 4096 + tid * 8;
    int row = flat >> 8, col = flat & 255;
    *(bf16x8*)(Pb + (long)(m0 + row) * Sc + n0 + col) =
        *(const bf16x8*)(sT + row * 256 + (col ^ (((row >> 2) & 3) << 4)));
  }
}

// ---------------------------------------------------------------------------
// t5 body: T = x * G (split, 3-MFMA) at 256x128/BK=32, 512 threads, 8 waves
// as 4x2 (wave tile 64x64). 2 barriers/tile (R6, verified R7). Single vmwait
// W=4; tails <4,SAL> then <0>.
// ---------------------------------------------------------------------------
struct TCtx {
  const __bf16 *pAh, *pAl, *pBh, *pBl;
  __bf16* lds;
  int stA, stB;                          // wave*1024 (A), wave*512 (B)
  int aoff, boff;
};

template <int W, bool SAL, bool S2AB, bool S2B>
__device__ __forceinline__ void tile_step_t(const TCtx& c, int t,
                                            floatx4 (&acc)[4][4]) {
  constexpr int K = 1024;
  constexpr int BH = 8192, BL = 12288, AL = 16384, BUF = 24576;
  __bf16* cur = c.lds + (t & 1) * BUF;
  __bf16* oth = c.lds + ((t & 1) ^ 1) * BUF;
  bf16x8 af[4], bfr[4], bfl[4], afl[4];

  vmwait<W>();
  bar_raw();
  if (SAL) {
    const __bf16* s = c.pAl + (t + 1) * 32;
    stage16(s, oth + AL + c.stA);
    stage16(s + 16 * K, oth + AL + c.stA + 512);
  }
#pragma unroll
  for (int mt = 0; mt < 4; ++mt)
    af[mt] = *(const bf16x8*)(cur + c.aoff + mt * 512);
#pragma unroll
  for (int nt = 0; nt < 4; ++nt)
    bfr[nt] = *(const bf16x8*)(cur + BH + c.boff + nt * 512);
#pragma unroll
  for (int nt = 0; nt < 4; ++nt)
    bfl[nt] = *(const bf16x8*)(cur + BL + c.boff + nt * 512);
#pragma unroll
  for (int mt = 0; mt < 4; ++mt)
    afl[mt] = *(const bf16x8*)(cur + AL + c.aoff + mt * 512);

  __builtin_amdgcn_s_setprio(1);
#pragma unroll
  for (int mt = 0; mt < 4; ++mt)
#pragma unroll
    for (int nt = 0; nt < 4; ++nt)
      acc[mt][nt] = __builtin_amdgcn_mfma_f32_16x16x32_bf16(af[mt], bfr[nt], acc[mt][nt], 0, 0, 0);
#pragma unroll
  for (int mt = 0; mt < 4; ++mt)
#pragma unroll
    for (int nt = 0; nt < 4; ++nt)
      acc[mt][nt] = __builtin_amdgcn_mfma_f32_16x16x32_bf16(af[mt], bfl[nt], acc[mt][nt], 0, 0, 0);
#pragma unroll
  for (int mt = 0; mt < 4; ++mt)
#pragma unroll
    for (int nt = 0; nt < 4; ++nt)
      acc[mt][nt] = __builtin_amdgcn_mfma_f32_16x16x32_bf16(afl[mt], bfr[nt], acc[mt][nt], 0, 0, 0);
  __builtin_amdgcn_s_setprio(0);

  bar_raw();   // all reads consumed -> safe to overwrite cur
  if (S2AB) {
    const __bf16* sa = c.pAh + (t + 2) * 32;
    stage16(sa, cur + c.stA);
    stage16(sa + 16 * K, cur + c.stA + 512);
    stage16(c.pBh + (t + 2) * 32, cur + BH + c.stB);
  }
  if (S2B) stage16(c.pBl + (t + 2) * 32, cur + BL + c.stB);
}

__device__ void t5_body(__bf16* smem,
    const __bf16* __restrict__ xhi, const __bf16* __restrict__ xlo,
    const __bf16* __restrict__ gthi, const __bf16* __restrict__ gtlo,
    __bf16* __restrict__ thi, __bf16* __restrict__ tlo, int bx, int by) {
  constexpr int K = 1024;
  const int m0   = by * 256;
  const int n0   = bx * 128;
  const int wave = threadIdx.x >> 6;
  const int lane = threadIdx.x & 63;
  const int wm   = wave >> 1;            // 0..3
  const int wn   = wave & 1;             // 0..1
  const int sr   = lane >> 2;
  const int scol = ((lane & 3) ^ ((sr >> 1) & 3)) * 8;
  const int frow = lane & 15;
  const int pko  = ((lane >> 4) ^ ((frow >> 1) & 3)) * 8;

  TCtx c;
  const long ar = (long)(m0 + wave * 32 + sr) * K + scol;
  const long br = (long)(n0 + wave * 16 + sr) * K + scol;
  c.pAh = xhi + ar;
  c.pAl = xlo + ar;
  c.pBh = gthi + br;
  c.pBl = gtlo + br;
  c.lds = smem;
  c.stA = wave * 1024;
  c.stB = wave * 512;
  c.aoff = (wm * 64 + frow) * 32 + pko;
  c.boff = (wn * 64 + frow) * 32 + pko;

  // Prologue (FIFO-order-critical): Ah0 x2, Bh0, Bl0, Al0 x2, Ah1 x2, Bh1, Bl1.
  {
    __bf16* b0 = smem;
    __bf16* b1 = smem + 24576;
    stage16(c.pAh, b0 + c.stA);          stage16(c.pAh + 16 * K, b0 + c.stA + 512);
    stage16(c.pBh, b0 + 8192 + c.stB);
    stage16(c.pBl, b0 + 12288 + c.stB);
    stage16(c.pAl, b0 + 16384 + c.stA);  stage16(c.pAl + 16 * K, b0 + 16384 + c.stA + 512);
    stage16(c.pAh + 32, b1 + c.stA);     stage16(c.pAh + 32 + 16 * K, b1 + c.stA + 512);
    stage16(c.pBh + 32, b1 + 8192 + c.stB);
    stage16(c.pBl + 32, b1 + 12288 + c.stB);
  }

  floatx4 acc[4][4];
  const floatx4 zero = {0.f, 0.f, 0.f, 0.f};
#pragma unroll
  for (int i = 0; i < 4; ++i)
#pragma unroll
    for (int j = 0; j < 4; ++j) acc[i][j] = zero;

#pragma unroll 1
  for (int t = 0; t < 30; ++t) tile_step_t<4, true, true, true>(c, t, acc);
  tile_step_t<4, true, false, false>(c, 30, acc);
  tile_step_t<0, false, false, false>(c, 31, acc);

  // ---- epilogue: hi/lo split via XOR-swizzled [256][128] LDS round-trip ----
  const int crow0 = (lane >> 4) * 4;
  const int ccol  = lane & 15;
  const int tid   = threadIdx.x;
  __bf16* sT = smem;                     // 64 KB
#pragma unroll 1
  for (int pass = 0; pass < 2; ++pass) {
    __syncthreads();
#pragma unroll
    for (int nt = 0; nt < 4; ++nt) {
      int col = wn * 64 + nt * 16 + ccol;
#pragma unroll
      for (int mt = 0; mt < 4; ++mt) {
        int rowb = wm * 64 + mt * 16 + crow0;
#pragma unroll
        for (int r = 0; r < 4; ++r) {
          int row = rowb + r;
          float v = acc[mt][nt][r];
          __bf16 h = f2bf(v);
          sT[row * 128 + (col ^ (((row >> 2) & 3) << 4))] =
              pass ? f2bf(v - bf2f(h)) : h;
        }
      }
    }
    __syncthreads();
    __bf16* dst = pass ? tlo : thi;
#pragma unroll
    for (int cc = 0; cc < 8; ++cc) {
      int flat = cc * 4096 + tid * 8;
      int row = flat >> 7, col = flat & 127;
      *(bf16x8*)(dst + (long)(m0 + row) * DKc + n0 + col) =
          *(const bf16x8*)(sT + row * 128 + (col ^ (((row >> 2) & 3) << 4)));
    }
  }
}

// ---------------------------------------------------------------------------
// Shared 2-phase/3-buffer counted-vmcnt NT GEMM step (R6: ONE barrier/tile).
// {vmwait W, bar, 6 stages, 16 reads, 32 MFMA}. Steady W=6; tails
// <6,no-stg> then <0>. Verified R7/R9/R11.
// Buffer regions (elems): A0=0, A1=8192, B0=16384, B1=20480; buffer=24576.
// ---------------------------------------------------------------------------
struct PCtx {
  const __bf16 *pA, *pB;
  int stA, stB;                          // wave*1024 (A), wave*512 (B)
  int aoff, boff;
};

template <int KK, int W, bool STG>
__device__ __forceinline__ void tile_step_pv(const PCtx& c, int t,
                                             __bf16* cur, __bf16* dst,
                                             floatx4 (&acc)[4][4]) {
  vmwait<W>();
  bar_raw();
  if (STG) {
    const __bf16* a = c.pA + (t + 2) * 64;
    stage16(a, dst + c.stA);
    stage16(a + 16 * KK, dst + c.stA + 512);
    stage16(c.pB + (t + 2) * 64, dst + 16384 + c.stB);
    stage16(a + 32, dst + 8192 + c.stA);
    stage16(a + 32 + 16 * KK, dst + 8192 + c.stA + 512);
    stage16(c.pB + (t + 2) * 64 + 32, dst + 20480 + c.stB);
  }
  bf16x8 a0[4], b0[4], a1[4], b1[4];
#pragma unroll
  for (int mt = 0; mt < 4; ++mt)
    a0[mt] = *(const bf16x8*)(cur + c.aoff + mt * 512);
#pragma unroll
  for (int nt = 0; nt < 4; ++nt)
    b0[nt] = *(const bf16x8*)(cur + 16384 + c.boff + nt * 512);
#pragma unroll
  for (int mt = 0; mt < 4; ++mt)
    a1[mt] = *(const bf16x8*)(cur + 8192 + c.aoff + mt * 512);
#pragma unroll
  for (int nt = 0; nt < 4; ++nt)
    b1[nt] = *(const bf16x8*)(cur + 20480 + c.boff + nt * 512);
  __builtin_amdgcn_s_setprio(1);
#pragma unroll
  for (int mt = 0; mt < 4; ++mt)
#pragma unroll
    for (int nt = 0; nt < 4; ++nt)
      acc[mt][nt] = __builtin_amdgcn_mfma_f32_16x16x32_bf16(a0[mt], b0[nt], acc[mt][nt], 0, 0, 0);
#pragma unroll
  for (int mt = 0; mt < 4; ++mt)
#pragma unroll
    for (int nt = 0; nt < 4; ++nt)
      acc[mt][nt] = __builtin_amdgcn_mfma_f32_16x16x32_bf16(a1[mt], b1[nt], acc[mt][nt], 0, 0, 0);
  __builtin_amdgcn_s_setprio(0);
}

// ---------------------------------------------------------------------------
// v4 body: Vt = (x*WV)^T, 1-barrier pipeline (KK=1024, 16 K-tiles).
// Epilogue: transpose via padded LDS [128][VSTR2=264], 16B stores.
// ---------------------------------------------------------------------------
constexpr int VSTR2 = 264;

__device__ void v4_body(__bf16* smem,
    const __bf16* __restrict__ xhi, const __bf16* __restrict__ wvthi,
    __bf16* __restrict__ vt, int bx, int by) {
  constexpr int K = 1024;
  const int m0   = by * 256;             // seq (flattened b*S)
  const int n0   = bx * 128;             // dk
  const int wave = threadIdx.x >> 6;
  const int lane = threadIdx.x & 63;
  const int wm   = wave >> 1;            // 0..3
  const int wn   = wave & 1;             // 0..1
  const int sr   = lane >> 2;
  const int scol = ((lane & 3) ^ ((sr >> 1) & 3)) * 8;
  const int frow = lane & 15;
  const int pko  = ((lane >> 4) ^ ((frow >> 1) & 3)) * 8;

  PCtx c;
  c.pA = xhi + (long)(m0 + wave * 32 + sr) * K + scol;
  c.pB = wvthi + (long)(n0 + wave * 16 + sr) * K + scol;
  c.stA = wave * 1024;
  c.stB = wave * 512;
  c.aoff = (wm * 64 + frow) * 32 + pko;
  c.boff = (wn * 64 + frow) * 32 + pko;

  __bf16* B0 = smem;
  __bf16* B1 = smem + 24576;
  __bf16* B2 = smem + 49152;

  // Prologue (FIFO-order-critical): t0 {A0 x2, B0, A1 x2, B1}, t1 same.
  stage16(c.pA, B0 + c.stA);            stage16(c.pA + 16 * K, B0 + c.stA + 512);
  stage16(c.pB, B0 + 16384 + c.stB);
  stage16(c.pA + 32, B0 + 8192 + c.stA); stage16(c.pA + 32 + 16 * K, B0 + 8192 + c.stA + 512);
  stage16(c.pB + 32, B0 + 20480 + c.stB);
  stage16(c.pA + 64, B1 + c.stA);       stage16(c.pA + 64 + 16 * K, B1 + c.stA + 512);
  stage16(c.pB + 64, B1 + 16384 + c.stB);
  stage16(c.pA + 96, B1 + 8192 + c.stA); stage16(c.pA + 96 + 16 * K, B1 + 8192 + c.stA + 512);
  stage16(c.pB + 96, B1 + 20480 + c.stB);

  floatx4 acc[4][4];
  const floatx4 zero = {0.f, 0.f, 0.f, 0.f};
#pragma unroll
  for (int i = 0; i < 4; ++i)
#pragma unroll
    for (int j = 0; j < 4; ++j) acc[i][j] = zero;

#pragma unroll 1
  for (int t = 0; t < 12; t += 3) {
    tile_step_pv<1024, 6, true>(c, t,     B0, B2, acc);
    tile_step_pv<1024, 6, true>(c, t + 1, B1, B0, acc);
    tile_step_pv<1024, 6, true>(c, t + 2, B2, B1, acc);
  }
  tile_step_pv<1024, 6, true >(c, 12, B0, B2, acc);
  tile_step_pv<1024, 6, true >(c, 13, B1, B0, acc);
  tile_step_pv<1024, 6, false>(c, 14, B2, B2, acc);
  tile_step_pv<1024, 0, false>(c, 15, B0, B0, acc);

  // ---- epilogue: transpose via padded LDS, 16B stores to vt[b][dk][s] ----
  const int crow0 = (lane >> 4) * 4;
  const int ccol  = lane & 15;
  const int tid   = threadIdx.x;
  __syncthreads();
  __bf16* sT = smem;                     // [128][VSTR2]
#pragma unroll
  for (int nt = 0; nt < 4; ++nt) {
    int nl = wn * 64 + nt * 16 + ccol;   // dk-local 0..127
#pragma unroll
    for (int mt = 0; mt < 4; ++mt) {
      int ml = wm * 64 + mt * 16 + crow0;  // seq-local 0..255
#pragma unroll
      for (int r = 0; r < 4; ++r)
        sT[(long)nl * VSTR2 + ml + r] = f2bf(acc[mt][nt][r]);
    }
  }
  __syncthreads();
  const int bb   = m0 >> 11;            // tile fully within one batch
  const int seq0 = m0 & (Sc - 1);
  __bf16* dst = vt + (long)bb * DKc * Sc + seq0;
#pragma unroll
  for (int cc = 0; cc < 8; ++cc) {
    int flat = cc * 4096 + tid * 8;     // logical 128x256; 16B per thread
    int row = flat >> 8, col = flat & 255;
    *(bf16x8*)(dst + (long)(n0 + row) * Sc + col) =
        *(const bf16x8*)(sT + (long)row * VSTR2 + col);
  }
}

// ---------------------------------------------------------------------------
// gemm_tv: fused T-GEMM (blocks 0..255) + V-GEMM (blocks 256..511).
// Verified R9/R11 (tail overlap win).
// ---------------------------------------------------------------------------
__global__ __launch_bounds__(512, 2) void gemm_tv(
    const __bf16* __restrict__ xhi, const __bf16* __restrict__ xlo,
    const __bf16* __restrict__ gthi, const __bf16* __restrict__ gtlo,
    __bf16* __restrict__ thi, __bf16* __restrict__ tlo,
    const __bf16* __restrict__ wvthi, __bf16* __restrict__ vt) {
  __shared__ __align__(16) __bf16 smem[73728];   // 144 KB (v-part max)
  int bid = blockIdx.x;
  if (bid < 256) {
    t5_body(smem, xhi, xlo, gthi, gtlo, thi, tlo, bid & 7, bid >> 3);
  } else {
    bid -= 256;
    v4_body(smem, xhi, wvthi, vt, bid & 7, bid >> 3);
  }
}

// ---------------------------------------------------------------------------
// scale_p: P <- P .* ffac[b][t(q)][k]  (elementwise, memory-bound).
// q-tiles are 256 rows (gemm_s5).
// ---------------------------------------------------------------------------
__global__ __launch_bounds__(256) void scale_p(__bf16* __restrict__ P,
                                               const float* __restrict__ ffac) {
  long i8 = (long)blockIdx.x * 256 + threadIdx.x;
  long base = i8 * 8;
  int k = (int)(base & (Sc - 1));
  int q = (int)((base >> 11) & (Sc - 1));
  int b = (int)(base >> 22);
  int t = q >> 8;                         // 256-row q-tiles
  const float* f = ffac + (((long)b * 8 + t) << 11) + k;
  float4 f0 = *(const float4*)f;
  float4 f1 = *(const float4*)(f + 4);
  bf16x8 p = *(const bf16x8*)(P + base);
  bf16x8 o;
  o[0] = f2bf(bf2f(p[0]) * f0.x);
  o[1] = f2bf(bf2f(p[1]) * f0.y);
  o[2] = f2bf(bf2f(p[2]) * f0.z);
  o[3] = f2bf(bf2f(p[3]) * f0.w);
  o[4] = f2bf(bf2f(p[4]) * f1.x);
  o[5] = f2bf(bf2f(p[5]) * f1.y);
  o[6] = f2bf(bf2f(p[6]) * f1.z);
  o[7] = f2bf(bf2f(p[7]) * f1.w);
  *(bf16x8*)(P + base) = o;
}

// ---------------------------------------------------------------------------
// gemm_pv4: out = attn @ Vt^T, plain NT GEMM (1-barrier pipeline). Verified R7.
// ---------------------------------------------------------------------------
__global__ __launch_bounds__(512, 2) void gemm_pv4(
    const __bf16* __restrict__ P, const __bf16* __restrict__ vt,
    float* __restrict__ out) {
  __shared__ __align__(16) __bf16 smem[73728];   // 144 KB = 3 x 48 KB buffers
  constexpr int K = 2048;
  const int b    = blockIdx.z;
  const int m0   = blockIdx.x * 256;     // q   (x=q: P-panel XCD locality)
  const int n0   = blockIdx.y * 128;     // dk
  const int wave = threadIdx.x >> 6;
  const int lane = threadIdx.x & 63;
  const int wm   = wave >> 1;            // 0..3
  const int wn   = wave & 1;             // 0..1
  const int sr   = lane >> 2;
  const int scol = ((lane & 3) ^ ((sr >> 1) & 3)) * 8;
  const int frow = lane & 15;
  const int pko  = ((lane >> 4) ^ ((frow >> 1) & 3)) * 8;

  PCtx c;
  c.pA = P + (long)b * Sc * Sc + (long)(m0 + wave * 32 + sr) * K + scol;
  c.pB = vt + (long)b * DKc * Sc + (long)(n0 + wave * 16 + sr) * K + scol;
  c.stA = wave * 1024;
  c.stB = wave * 512;
  c.aoff = (wm * 64 + frow) * 32 + pko;
  c.boff = (wn * 64 + frow) * 32 + pko;

  __bf16* B0 = smem;
  __bf16* B1 = smem + 24576;
  __bf16* B2 = smem + 49152;

  // Prologue (FIFO-order-critical): t0 {A0 x2, B0, A1 x2, B1}, t1 same.
  stage16(c.pA, B0 + c.stA);            stage16(c.pA + 16 * K, B0 + c.stA + 512);
  stage16(c.pB, B0 + 16384 + c.stB);
  stage16(c.pA + 32, B0 + 8192 + c.stA); stage16(c.pA + 32 + 16 * K, B0 + 8192 + c.stA + 512);
  stage16(c.pB + 32, B0 + 20480 + c.stB);
  stage16(c.pA + 64, B1 + c.stA);       stage16(c.pA + 64 + 16 * K, B1 + c.stA + 512);
  stage16(c.pB + 64, B1 + 16384 + c.stB);
  stage16(c.pA + 96, B1 + 8192 + c.stA); stage16(c.pA + 96 + 16 * K, B1 + 8192 + c.stA + 512);
  stage16(c.pB + 96, B1 + 20480 + c.stB);

  floatx4 acc[4][4];
  const floatx4 zero = {0.f, 0.f, 0.f, 0.f};
#pragma unroll
  for (int i = 0; i < 4; ++i)
#pragma unroll
    for (int j = 0; j < 4; ++j) acc[i][j] = zero;

#pragma unroll 1
  for (int t = 0; t < 30; t += 3) {
    tile_step_pv<2048, 6, true>(c, t,     B0, B2, acc);
    tile_step_pv<2048, 6, true>(c, t + 1, B1, B0, acc);
    tile_step_pv<2048, 6, true>(c, t + 2, B2, B1, acc);
  }
  tile_step_pv<2048, 6, false>(c, 30, B0, B0, acc);
  tile_step_pv<2048, 0, false>(c, 31, B1, B1, acc);

  // ---- epilogue: direct fp32 store ----
  const int crow0 = (lane >> 4) * 4;
  const int ccol  = lane & 15;
#pragma unroll
  for (int nt = 0; nt < 4; ++nt) {
    int cn = n0 + wn * 64 + nt * 16 + ccol;
#pragma unroll
    for (int mt = 0; mt < 4; ++mt) {
#pragma unroll
      for (int r = 0; r < 4; ++r) {
        int cm_ = m0 + wm * 64 + mt * 16 + crow0 + r;
        out[(long)b * Sc * DKc + (long)cm_ * DKc + cn] = acc[mt][nt][r];
      }
    }
  }
}

// ---------------------------------------------------------------------------
// gemm_g64b: Gt[m][n] = sum_k WK[m,k]WQ[n,k] (split, 3-MFMA), 64x64 tiles,
// R12: counted-vmcnt double-buffered port of the old 2-barrier g64.
// 4 loads/thread/tile {Ah,Al,Bh,Bl}; double buffer 2 x 16 KB; schedule
// {vmwait<W>, bar, 8 frag reads, 12 MFMA, bar, stage t+2}. Ledger: prologue
// 8 (t0,t1); steady W=4 (drains exactly tile t's 4, leaves t+1's); tails
// <4,no-stg> then <0>. Regions/buffer (elems): AH=0, BH=2048, AL=4096,
// BL=6144; buffer=8192.
// ---------------------------------------------------------------------------
struct GCtx {
  const __bf16 *pAh, *pAl, *pBh, *pBl;
  __bf16* lds;
  int stLds;                             // wave*16 rows * 32 = wave*512
  int aoff, boff;
};

template <int W, bool STG>
__device__ __forceinline__ void tile_step_g(const GCtx& c, int t,
                                            floatx4 (&acc)[2][2]) {
  constexpr int BH = 2048, AL = 4096, BL = 6144, BUF = 8192;
  __bf16* cur = c.lds + (t & 1) * BUF;
  bf16x8 af[2], bfr[2], afl[2], bfl[2];

  vmwait<W>();
  bar_raw();
#pragma unroll
  for (int i = 0; i < 2; ++i) {
    af[i]  = *(const bf16x8*)(cur + c.aoff + i * 512);
    bfr[i] = *(const bf16x8*)(cur + BH + c.boff + i * 512);
    afl[i] = *(const bf16x8*)(cur + AL + c.aoff + i * 512);
    bfl[i] = *(const bf16x8*)(cur + BL + c.boff + i * 512);
  }
  __builtin_amdgcn_s_setprio(1);
#pragma unroll
  for (int mt = 0; mt < 2; ++mt)
#pragma unroll
    for (int nt = 0; nt < 2; ++nt) {
      acc[mt][nt] = __builtin_amdgcn_mfma_f32_16x16x32_bf16(af[mt], bfr[nt], acc[mt][nt], 0, 0, 0);
      acc[mt][nt] = __builtin_amdgcn_mfma_f32_16x16x32_bf16(af[mt], bfl[nt], acc[mt][nt], 0, 0, 0);
      acc[mt][nt] = __builtin_amdgcn_mfma_f32_16x16x32_bf16(afl[mt], bfr[nt], acc[mt][nt], 0, 0, 0);
    }
  __builtin_amdgcn_s_setprio(0);

  bar_raw();   // all waves consumed cur -> safe to overwrite (t+2 same parity)
  if (STG) {
    const int o = (t + 2) * 32;
    stage16(c.pAh + o, cur + c.stLds);
    stage16(c.pAl + o, cur + AL + c.stLds);
    stage16(c.pBh + o, cur + BH + c.stLds);
    stage16(c.pBl + o, cur + BL + c.stLds);
  }
}

__global__ __launch_bounds__(256) void gemm_g64b(
    const __bf16* __restrict__ Ahi, const __bf16* __restrict__ Alo,
    const __bf16* __restrict__ Bhi, const __bf16* __restrict__ Blo,
    __bf16* __restrict__ Chi, __bf16* __restrict__ Clo) {
  constexpr int K = Dc, N = DKc;
  __shared__ __align__(16) __bf16 smem[16384];   // 32 KB: 2 x {Ah,Bh,Al,Bl}
  const int wave = threadIdx.x >> 6;
  const int lane = threadIdx.x & 63;
  const int wm   = wave >> 1, wn = wave & 1;
  const int m0   = blockIdx.y * 64;
  const int n0   = blockIdx.x * 64;

  const int sr   = lane >> 2;
  const int scol = ((lane & 3) ^ ((sr >> 1) & 3)) * 8;
  const int frow = lane & 15;
  const int pko  = ((lane >> 4) ^ ((frow >> 1) & 3)) * 8;

  GCtx c;
  const long ga = (long)(m0 + wave * 16 + sr) * K + scol;
  const long gb = (long)(n0 + wave * 16 + sr) * K + scol;
  c.pAh = Ahi + ga;
  c.pAl = Alo + ga;
  c.pBh = Bhi + gb;
  c.pBl = Blo + gb;
  c.lds = smem;
  c.stLds = wave * 512;
  c.aoff = (wm * 32 + frow) * 32 + pko;
  c.boff = (wn * 32 + frow) * 32 + pko;

  // Prologue: t0 {Ah,Al,Bh,Bl}, t1 {Ah,Al,Bh,Bl} (8 loads).
  {
    __bf16* b0 = smem;
    __bf16* b1 = smem + 8192;
    stage16(c.pAh, b0 + c.stLds);
    stage16(c.pAl, b0 + 4096 + c.stLds);
    stage16(c.pBh, b0 + 2048 + c.stLds);
    stage16(c.pBl, b0 + 6144 + c.stLds);
    stage16(c.pAh + 32, b1 + c.stLds);
    stage16(c.pAl + 32, b1 + 4096 + c.stLds);
    stage16(c.pBh + 32, b1 + 2048 + c.stLds);
    stage16(c.pBl + 32, b1 + 6144 + c.stLds);
  }

  floatx4 acc[2][2];
  const floatx4 zero = {0.f, 0.f, 0.f, 0.f};
#pragma unroll
  for (int i = 0; i < 2; ++i)
#pragma unroll
    for (int j = 0; j < 2; ++j) acc[i][j] = zero;

#pragma unroll 1
  for (int t = 0; t < 30; ++t) tile_step_g<4, true>(c, t, acc);
  tile_step_g<4, false>(c, 30, acc);
  tile_step_g<0, false>(c, 31, acc);

  // ---- epilogue: hi/lo split via [64][64] LDS round-trip (unchanged) ----
  const int crow0 = (lane >> 4) * 4;
  const int ccol  = lane & 15;
  const int tid   = threadIdx.x;
  __bf16* sT = smem;                     // [64][64] = 8KB
#pragma unroll 1
  for (int pass = 0; pass < 2; ++pass) {
    __syncthreads();
#pragma unroll
    for (int nt = 0; nt < 2; ++nt) {
      int col = wn * 32 + nt * 16 + ccol;
#pragma unroll
      for (int mt = 0; mt < 2; ++mt) {
        int row = wm * 32 + mt * 16 + crow0;
#pragma unroll
        for (int r = 0; r < 4; ++r) {
          float v = acc[mt][nt][r];
          __bf16 h = f2bf(v);
          sT[(row + r) * 64 + col] = pass ? f2bf(v - bf2f(h)) : h;
        }
      }
    }
    __syncthreads();
    __bf16* dst = pass ? Clo : Chi;
#pragma unroll
    for (int cc = 0; cc < 2; ++cc) {
      int flat = cc * 2048 + tid * 8;
      int row = flat >> 6, col = flat & 63;
      *(bf16x8*)(dst + (long)(m0 + row) * N + n0 + col) = *(const bf16x8*)(sT + flat);
    }
  }
}

// ---------------------------------------------------------------------------
// Fold 8 q-tile partials -> ffac[b][t][k] = exp(M_t - M_k) / Z_k.
// ---------------------------------------------------------------------------
__global__ __launch_bounds__(256) void softmax_reduce(const float* __restrict__ Pmax,
                                                      const float* __restrict__ Psum,
                                                      float* __restrict__ Ffac) {
  int idx = blockIdx.x * 256 + threadIdx.x;   // b*2048 + k
  int b = idx >> 11, k = idx & (Sc - 1);
  const float* pm = Pmax + (long)b * 8 * Sc + k;
  const float* ps = Psum + (long)b * 8 * Sc + k;
  float M = -3.0e38f;
#pragma unroll
  for (int t = 0; t < 8; ++t) M = fmaxf(M, pm[(long)t * Sc]);
  float S = 0.f;
#pragma unroll
  for (int t = 0; t < 8; ++t)
    S += ps[(long)t * Sc] * __expf(pm[(long)t * Sc] - M);
  float inv = 1.0f / S;
  float* fo = Ffac + (long)b * 8 * Sc + k;
#pragma unroll
  for (int t = 0; t < 8; ++t)
    fo[(long)t * Sc] = __expf(pm[(long)t * Sc] - M) * inv;
}

// ---------------------------------------------------------------------------
extern "C" void kernel_launch(void* const* d_in, const int* in_sizes, int n_in,
                              void* d_out, int out_size, void* d_ws, size_t ws_size,
                              hipStream_t stream) {
  const float* x  = (const float*)d_in[0];
  const float* WQ = (const float*)d_in[1];
  const float* WK = (const float*)d_in[2];
  const float* WV = (const float*)d_in[3];
  float* out = (float*)d_out;
  char* ws = (char*)d_ws;
  const long MB = 1024L * 1024L;

  // Workspace layout (peak ~131 MB).
  __bf16* xhi  = (__bf16*)(ws + 0 * MB);     // 16 MB
  __bf16* xlo  = (__bf16*)(ws + 16 * MB);    // 16 MB
  __bf16* wqhi = (__bf16*)(ws + 32 * MB);    // 2 MB each (element-wise split)
  __bf16* wqlo = (__bf16*)(ws + 34 * MB);
  __bf16* wkhi = (__bf16*)(ws + 36 * MB);
  __bf16* wklo = (__bf16*)(ws + 38 * MB);
  __bf16* wvthi= (__bf16*)(ws + 40 * MB);    // transposed, hi only
  __bf16* gthi = (__bf16*)(ws + 44 * MB);    // 2 MB each: Gt = (WQ WK^T)^T
  __bf16* gtlo = (__bf16*)(ws + 46 * MB);
  __bf16* thi  = (__bf16*)(ws + 48 * MB);    // 16 MB each: T = x*G
  __bf16* tlo  = (__bf16*)(ws + 64 * MB);
  __bf16* vt   = (__bf16*)(ws + 80 * MB);    // 16 MB, [B][DK][S]
  __bf16* P    = (__bf16*)(ws + 96 * MB);    // 32 MB, p = exp(s - M_t), bf16
  float*  pmax = (float*)(ws + 128 * MB);    // [B][8][S]
  float*  psum = (float*)(ws + 129 * MB);
  float*  ffac = (float*)(ws + 130 * MB);    // [B][8][S]

  // 1. casts (float4-vectorized) + WV transpose (one dispatch)
  prep<<<11264, 256, 0, stream>>>(x, xhi, xlo, WQ, wqhi, wqlo, WK, wkhi, wklo,
                                  WV, wvthi);

  // 2. Gt[d][a] = G[a][d]: NT(A=WK, B=WQ), 64x64 tiles, counted-vmcnt.
  gemm_g64b<<<dim3(16, 16), 256, 0, stream>>>(wkhi, wklo, wqhi, wqlo, gthi, gtlo);

  // 3+4. Fused: T = x*G (blocks 0..255) and Vt = (x*WV)^T (blocks 256..511).
  gemm_tv<<<512, 512, 0, stream>>>(xhi, xlo, gthi, gtlo, thi, tlo, wvthi, vt);

  // 5. S = T*x^T * scale; emits p (bf16) + per-256-tile column max/expsum.
  gemm_s5<<<dim3(Sc / 256, Sc / 256, Bc), 512, 0, stream>>>(
      thi, tlo, xhi, xlo, P, pmax, psum);

  // 6. partials -> ffac (8 q-tiles)
  softmax_reduce<<<32, 256, 0, stream>>>(pmax, psum, ffac);

  // 7. P <- P .* ffac (elementwise).
  scale_p<<<8192, 256, 0, stream>>>(P, ffac);

  // 8. out = P @ Vt^T -- 1-barrier pipeline.
  gemm_pv4<<<dim3(Sc / 256, DKc / 128, Bc), 512, 0, stream>>>(P, vt, out);
}